// Round 37
// baseline (594.179 us; speedup 1.0000x reference)
//
#include <hip/hip_runtime.h>

#define NN 50000
#define N2 100000
#define EE 500000
#define E2 1000000

typedef unsigned short u16;
typedef unsigned int u32;

typedef __attribute__((ext_vector_type(8))) __bf16 bf16x8;
typedef __attribute__((ext_vector_type(4))) float f32x4;

__device__ __forceinline__ float4 ld4(const float* p) { return *(const float4*)p; }

// round-to-nearest-even f32 -> bf16 bits
__device__ __forceinline__ u16 f2bf(float f) {
  u32 u = __float_as_uint(f);
  u += 0x7FFFu + ((u >> 16) & 1u);
  return (u16)(u >> 16);
}

// HW packed convert: low16 = bf16(lo), high16 = bf16(hi) (RNE)
__device__ __forceinline__ u32 cvtpk(float lo, float hi) {
  u32 r;
  asm("v_cvt_pk_bf16_f32 %0, %1, %2" : "=v"(r) : "v"(lo), "v"(hi));
  return r;
}

// fused constants kernel
__global__ void L384_const(const float* fc_w, const float* attn_l,
                           const float* attn_r, const float* Ww, float* w_r,
                           u16* wlB, u16* Bt, u16* Wt) {
  const int b = blockIdx.x;
  const int t = threadIdx.x;
  if (b < 256) {
    Bt[b * 256 + t] = f2bf(fc_w[(size_t)t * 256 + b]);
  } else if (b == 256) {
    for (int h = 0; h < 4; ++h) {
      float sl = 0.f, sr = 0.f;
      for (int d = 0; d < 64; ++d) {
        float f = fc_w[t * 256 + h * 64 + d];
        sl += f * attn_l[h * 64 + d];
        sr += f * attn_r[h * 64 + d];
      }
      w_r[t * 4 + h] = sr;
      wlB[h * 256 + t] = f2bf(sl);
    }
    for (int h = 4; h < 16; ++h) wlB[h * 256 + t] = 0;
  } else {
    int n = b - 257;
    for (int k = t; k < 320; k += 256)
      Wt[(size_t)n * 320 + k] = f2bf(Ww[(size_t)k * 128 + n]);
  }
}

// prep over 2NN dst rows only: X[r][64..320) = bf16(dst feats); er = dst . w_r
__global__ void L384_prep(const float* Du, const float* Di, const float* w_r_,
                          u16* X, float* er) {
  const int r = blockIdx.x * 4 + (threadIdx.x >> 6);
  const int lane = threadIdx.x & 63;
  if (r >= N2) return;
  const float* src = (r < NN) ? Du + (size_t)r * 256 : Di + (size_t)(r - NN) * 256;
  float4 xv = ld4(src + lane * 4);
  uint2 pk = make_uint2(cvtpk(xv.x, xv.y), cvtpk(xv.z, xv.w));
  *(uint2*)(X + (size_t)r * 320 + 64 + lane * 4) = pk;
  const float* wr = w_r_ + lane * 16;
  float4 w0 = ld4(wr), w1 = ld4(wr + 4), w2 = ld4(wr + 8), w3 = ld4(wr + 12);
  float a0 = xv.x * w0.x + xv.y * w1.x + xv.z * w2.x + xv.w * w3.x;
  float a1 = xv.x * w0.y + xv.y * w1.y + xv.z * w2.y + xv.w * w3.y;
  float a2 = xv.x * w0.z + xv.y * w1.z + xv.z * w2.z + xv.w * w3.z;
  float a3 = xv.x * w0.w + xv.y * w1.w + xv.z * w2.w + xv.w * w3.w;
  for (int off = 32; off; off >>= 1) {
    a0 += __shfl_xor(a0, off);
    a1 += __shfl_xor(a1, off);
    a2 += __shfl_xor(a2, off);
    a3 += __shfl_xor(a3, off);
  }
  if (lane == 0) {
    float* op = er + (size_t)r * 4;
    op[0] = a0; op[1] = a1; op[2] = a2; op[3] = a3;
  }
}

// gemm: fs = bf16(Asrc) @ fc_w; el = Asrc @ w_l (wlB MFMA, once per block).
__global__ __launch_bounds__(512) void L384_gemm(const float* Au, const float* Ai,
                                                 const u16* Bt, const u16* wlB,
                                                 u16* C, float* el) {
  __shared__ u16 bs[64][264];
  const int t = threadIdx.x;
  const int w = t >> 6;
  const int l = t & 63;
  const int lr = l & 15;
  const int kg = l >> 4;
  const int row0 = blockIdx.x * 128;

  const int row = row0 + w * 16 + lr;
  const int rr = (row < N2) ? row : (N2 - 1);
  const float* arow =
      ((rr < NN) ? Au + (size_t)rr * 256 : Ai + (size_t)(rr - NN) * 256) + kg * 8;
  uint4 a[8];
#pragma unroll
  for (int ks = 0; ks < 8; ++ks) {
    float4 f0 = ld4(arow + ks * 32);
    float4 f1 = ld4(arow + ks * 32 + 4);
    a[ks] = make_uint4(cvtpk(f0.x, f0.y), cvtpk(f0.z, f0.w), cvtpk(f1.x, f1.y),
                       cvtpk(f1.z, f1.w));
  }

  {
    f32x4 eacc = {0.f, 0.f, 0.f, 0.f};
    const u16* wl = wlB + lr * 256 + kg * 8;
#pragma unroll
    for (int ks = 0; ks < 8; ++ks) {
      union { bf16x8 v; uint4 q; } af, wf;
      af.q = a[ks];
      wf.q = *(const uint4*)(wl + ks * 32);
      eacc = __builtin_amdgcn_mfma_f32_16x16x32_bf16(af.v, wf.v, eacc, 0, 0, 0);
    }
    if (lr < 4) {
#pragma unroll
      for (int r = 0; r < 4; ++r) {
        int grow = row0 + w * 16 + kg * 4 + r;
        if (grow < N2) el[(size_t)grow * 4 + lr] = eacc[r];
      }
    }
  }

  for (int strip = 0; strip < 4; ++strip) {
    __syncthreads();
    {
      const int brow = t >> 3;
      const int bc = (t & 7) * 32;
      const uint4* s = (const uint4*)(Bt + (size_t)(strip * 64 + brow) * 256 + bc);
      uint4* d = (uint4*)&bs[brow][bc];
      d[0] = s[0]; d[1] = s[1]; d[2] = s[2]; d[3] = s[3];
    }
    __syncthreads();

    f32x4 acc[4];
#pragma unroll
    for (int ct = 0; ct < 4; ++ct) acc[ct] = (f32x4){0.f, 0.f, 0.f, 0.f};
#pragma unroll
    for (int ks = 0; ks < 8; ++ks) {
      union { bf16x8 v; uint4 q; } af;
      af.q = a[ks];
#pragma unroll
      for (int ct = 0; ct < 4; ++ct) {
        union { bf16x8 v; uint4 q; } b;
        b.q = *(const uint4*)&bs[ct * 16 + lr][ks * 32 + kg * 8];
        acc[ct] = __builtin_amdgcn_mfma_f32_16x16x32_bf16(af.v, b.v, acc[ct], 0, 0, 0);
      }
    }

#pragma unroll
    for (int p = 0; p < 2; ++p) {
      __syncthreads();
      if ((w >> 2) == p) {
        const int lrow = (w & 3) * 16 + kg * 4;
#pragma unroll
        for (int ct = 0; ct < 4; ++ct)
#pragma unroll
          for (int r = 0; r < 4; ++r)
            bs[lrow + r][ct * 16 + lr] = f2bf(acc[ct][r]);
      }
      __syncthreads();
      const int lrow2 = t >> 3;
      const int c0 = (t & 7) * 8;
      const int grow = row0 + p * 64 + lrow2;
      if (grow < N2)
        *(uint4*)(C + (size_t)grow * 256 + strip * 64 + c0) =
            *(const uint4*)&bs[lrow2][c0];
    }
  }
}

__global__ void L384_zero(int* p, int n) {
  int i = blockIdx.x * 256 + threadIdx.x;
  if (i < n) p[i] = 0;
}
__global__ void L384_hist(const int* i2u_dst, const int* u2i_dst, int* cnt) {
  int e = blockIdx.x * 256 + threadIdx.x;
  if (e < EE) {
    int d = i2u_dst[e];
    d = ((unsigned)d < NN) ? d : 0;
    atomicAdd(&cnt[d], 1);
  } else if (e < E2) {
    int d = u2i_dst[e - EE];
    d = ((unsigned)d < NN) ? d : 0;
    atomicAdd(&cnt[NN + d], 1);
  }
}
// single-block hierarchical exclusive scan over n counts -> indptr, cur
__global__ __launch_bounds__(1024) void L384_scan(const int* cnt, int* indptr,
                                                  int* cur, int n) {
  __shared__ int ws[16];
  const int t = threadIdx.x;
  const int chunk = (n + 1023) / 1024;
  const int base = t * chunk;
  const int end = (base + chunk < n) ? (base + chunk) : n;
  int sum = 0;
  for (int i = base; i < end; ++i) sum += cnt[i];
  const int lane = t & 63;
  const int wv = t >> 6;
  int v = sum;
  for (int off = 1; off < 64; off <<= 1) {
    int u = __shfl_up(v, off);
    if (lane >= off) v += u;
  }
  if (lane == 63) ws[wv] = v;
  __syncthreads();
  if (wv == 0 && lane < 16) {
    int u = ws[lane];
    for (int off = 1; off < 16; off <<= 1) {
      int x = __shfl_up(u, off);
      if (lane >= off) u += x;
    }
    ws[lane] = u;
  }
  __syncthreads();
  int waveOff = (wv > 0) ? ws[wv - 1] : 0;
  int run = waveOff + v - sum;  // exclusive prefix of this thread's chunk
  for (int i = base; i < end; ++i) {
    int c = cnt[i];
    indptr[i] = run;
    cur[i] = run;
    run += c;
  }
  if (t == 1023) indptr[n] = run;
}
__global__ void L384_fill(const int* i2u_src, const int* i2u_dst,
                          const int* u2i_src, const int* u2i_dst,
                          int* cur, int* csr) {
  int e = blockIdx.x * 256 + threadIdx.x;
  if (e < EE) {
    int d = i2u_dst[e];
    d = ((unsigned)d < NN) ? d : 0;
    int s = i2u_src[e];
    s = ((unsigned)s < NN) ? s : 0;
    int pos = atomicAdd(&cur[d], 1);
    if ((unsigned)pos < E2) csr[pos] = NN + s;
  } else if (e < E2) {
    int d = u2i_dst[e - EE];
    d = ((unsigned)d < NN) ? d : 0;
    int s = u2i_src[e - EE];
    s = ((unsigned)s < NN) ? s : 0;
    int pos = atomicAdd(&cur[NN + d], 1);
    if ((unsigned)pos < E2) csr[pos] = s;
  }
}
// LDS-staged per-node sort: block covers 256 nodes' contiguous CSR range.
__global__ void L384_sort(const int* indptr, int* csr, int n) {
  __shared__ int buf[5120];
  const int t = threadIdx.x;
  const int node0 = blockIdx.x * 256;
  const int nEnd = (node0 + 256 < n) ? (node0 + 256) : n;
  if (node0 >= n) return;
  const int segL = indptr[node0];
  const int segR = indptr[nEnd];
  const int len = segR - segL;
  if (len <= 5120) {
    for (int i = t; i < len; i += 256) buf[i] = csr[segL + i];
    __syncthreads();
    const int node = node0 + t;
    if (node < n) {
      int p0 = indptr[node] - segL;
      int p1 = indptr[node + 1] - segL;
      for (int a = p0 + 1; a < p1; ++a) {
        int v = buf[a];
        int b = a - 1;
        while (b >= p0 && buf[b] > v) {
          buf[b + 1] = buf[b];
          --b;
        }
        buf[b + 1] = v;
      }
    }
    __syncthreads();
    for (int i = t; i < len; i += 256) csr[segL + i] = buf[i];
  } else {
    const int node = node0 + t;
    if (node < n) {
      int p0 = indptr[node], p1 = indptr[node + 1];
      for (int a = p0 + 1; a < p1; ++a) {
        int v = csr[a];
        int b = a - 1;
        while (b >= p0 && csr[b] > v) {
          csr[b + 1] = csr[b];
          --b;
        }
        csr[b + 1] = v;
      }
    }
  }
}

// fused edge-softmax + aggregation: one wave per dst node.
// aL layout [slot][edge][head]: conflict-free broadcast reads in phase B.
__global__ void L384_aggx(const int* indptr, const int* csr, const float* el,
                          const float* er, const u16* fs, const float* bias,
                          float* alphaG, u16* X) {
  __shared__ float aL[4][64][4];
  __shared__ int sL[4][64];
  const int slot = threadIdx.x >> 6;
  const int wid = blockIdx.x * 4 + slot;
  const int lane = threadIdx.x & 63;
  if (wid >= N2) return;
  const int p0 = indptr[wid];
  const int deg = indptr[wid + 1] - p0;
  const int h = lane >> 4;
  const int c = lane & 15;
  float4 er4 = ld4(er + (size_t)wid * 4);

  const bool small = (deg <= 64);
  if (small) {
    float4 ex = {0.f, 0.f, 0.f, 0.f};
    int s = 0;
    if (lane < deg) {
      s = csr[p0 + lane];
      s = ((unsigned)s < N2) ? s : 0;
      float4 ev = ld4(el + (size_t)s * 4);
      float e0 = ev.x + er4.x; e0 = (e0 >= 0.f) ? e0 : 0.2f * e0;
      float e1 = ev.y + er4.y; e1 = (e1 >= 0.f) ? e1 : 0.2f * e1;
      float e2 = ev.z + er4.z; e2 = (e2 >= 0.f) ? e2 : 0.2f * e2;
      float e3 = ev.w + er4.w; e3 = (e3 >= 0.f) ? e3 : 0.2f * e3;
      ex = make_float4(__expf(e0), __expf(e1), __expf(e2), __expf(e3));
    }
    float d0 = ex.x, d1 = ex.y, d2 = ex.z, d3 = ex.w;
    for (int off = 32; off; off >>= 1) {
      d0 += __shfl_xor(d0, off);
      d1 += __shfl_xor(d1, off);
      d2 += __shfl_xor(d2, off);
      d3 += __shfl_xor(d3, off);
    }
    if (lane < deg) {
      float4 o = make_float4(ex.x / d0, ex.y / d1, ex.z / d2, ex.w / d3);
      *(float4*)&aL[slot][lane][0] = o;
      sL[slot][lane] = s;
    }
  } else if (deg > 0) {
    float d0 = 0.f, d1 = 0.f, d2 = 0.f, d3 = 0.f;
    for (int i = lane; i < deg; i += 64) {
      int s = csr[p0 + i];
      s = ((unsigned)s < N2) ? s : 0;
      float4 ev = ld4(el + (size_t)s * 4);
      float e0 = ev.x + er4.x; e0 = (e0 >= 0.f) ? e0 : 0.2f * e0;
      float e1 = ev.y + er4.y; e1 = (e1 >= 0.f) ? e1 : 0.2f * e1;
      float e2 = ev.z + er4.z; e2 = (e2 >= 0.f) ? e2 : 0.2f * e2;
      float e3 = ev.w + er4.w; e3 = (e3 >= 0.f) ? e3 : 0.2f * e3;
      float4 ex = make_float4(__expf(e0), __expf(e1), __expf(e2), __expf(e3));
      *(float4*)(alphaG + (size_t)(p0 + i) * 4) = ex;
      d0 += ex.x; d1 += ex.y; d2 += ex.z; d3 += ex.w;
    }
    for (int off = 32; off; off >>= 1) {
      d0 += __shfl_xor(d0, off);
      d1 += __shfl_xor(d1, off);
      d2 += __shfl_xor(d2, off);
      d3 += __shfl_xor(d3, off);
    }
    float i0 = 1.f / d0, i1 = 1.f / d1, i2 = 1.f / d2, i3 = 1.f / d3;
    for (int i = lane; i < deg; i += 64) {
      float4 ex = *(const float4*)(alphaG + (size_t)(p0 + i) * 4);
      *(float4*)(alphaG + (size_t)(p0 + i) * 4) =
          make_float4(ex.x * i0, ex.y * i1, ex.z * i2, ex.w * i3);
    }
  }

  float ax = 0.f, ay = 0.f, az = 0.f, aw = 0.f;
  int i = 0;
  for (; i + 4 <= deg; i += 4) {
    int s0, s1, s2, s3;
    float a0, a1, a2, a3;
    if (small) {
      s0 = sL[slot][i + 0]; s1 = sL[slot][i + 1];
      s2 = sL[slot][i + 2]; s3 = sL[slot][i + 3];
      a0 = aL[slot][i + 0][h]; a1 = aL[slot][i + 1][h];
      a2 = aL[slot][i + 2][h]; a3 = aL[slot][i + 3][h];
    } else {
      s0 = csr[p0 + i + 0]; s0 = ((unsigned)s0 < N2) ? s0 : 0;
      s1 = csr[p0 + i + 1]; s1 = ((unsigned)s1 < N2) ? s1 : 0;
      s2 = csr[p0 + i + 2]; s2 = ((unsigned)s2 < N2) ? s2 : 0;
      s3 = csr[p0 + i + 3]; s3 = ((unsigned)s3 < N2) ? s3 : 0;
      a0 = alphaG[(size_t)(p0 + i + 0) * 4 + h];
      a1 = alphaG[(size_t)(p0 + i + 1) * 4 + h];
      a2 = alphaG[(size_t)(p0 + i + 2) * 4 + h];
      a3 = alphaG[(size_t)(p0 + i + 3) * 4 + h];
    }
    uint2 q0 = *(const uint2*)(fs + (size_t)s0 * 256 + lane * 4);
    uint2 q1 = *(const uint2*)(fs + (size_t)s1 * 256 + lane * 4);
    uint2 q2 = *(const uint2*)(fs + (size_t)s2 * 256 + lane * 4);
    uint2 q3 = *(const uint2*)(fs + (size_t)s3 * 256 + lane * 4);
    ax += a0 * __uint_as_float(q0.x << 16);
    ay += a0 * __uint_as_float(q0.x & 0xffff0000u);
    az += a0 * __uint_as_float(q0.y << 16);
    aw += a0 * __uint_as_float(q0.y & 0xffff0000u);
    ax += a1 * __uint_as_float(q1.x << 16);
    ay += a1 * __uint_as_float(q1.x & 0xffff0000u);
    az += a1 * __uint_as_float(q1.y << 16);
    aw += a1 * __uint_as_float(q1.y & 0xffff0000u);
    ax += a2 * __uint_as_float(q2.x << 16);
    ay += a2 * __uint_as_float(q2.x & 0xffff0000u);
    az += a2 * __uint_as_float(q2.y << 16);
    aw += a2 * __uint_as_float(q2.y & 0xffff0000u);
    ax += a3 * __uint_as_float(q3.x << 16);
    ay += a3 * __uint_as_float(q3.x & 0xffff0000u);
    az += a3 * __uint_as_float(q3.y << 16);
    aw += a3 * __uint_as_float(q3.y & 0xffff0000u);
  }
  for (; i < deg; ++i) {
    int s0;
    float a0;
    if (small) {
      s0 = sL[slot][i];
      a0 = aL[slot][i][h];
    } else {
      s0 = csr[p0 + i]; s0 = ((unsigned)s0 < N2) ? s0 : 0;
      a0 = alphaG[(size_t)(p0 + i) * 4 + h];
    }
    uint2 q0 = *(const uint2*)(fs + (size_t)s0 * 256 + lane * 4);
    ax += a0 * __uint_as_float(q0.x << 16);
    ay += a0 * __uint_as_float(q0.x & 0xffff0000u);
    az += a0 * __uint_as_float(q0.y << 16);
    aw += a0 * __uint_as_float(q0.y & 0xffff0000u);
  }
  const float* bp = bias + lane * 4;
  float ox = ax + bp[0];
  float oy = ay + bp[1];
  float oz = az + bp[2];
  float ow = aw + bp[3];
  for (int off = 16; off <= 32; off <<= 1) {
    ox += __shfl_xor(ox, off);
    oy += __shfl_xor(oy, off);
    oz += __shfl_xor(oz, off);
    ow += __shfl_xor(ow, off);
  }
  if (h == 0) {
    uint2 pk = make_uint2(cvtpk(ox * 0.25f, oy * 0.25f), cvtpk(oz * 0.25f, ow * 0.25f));
    *(uint2*)(X + (size_t)wid * 320 + 4 * c) = pk;
  }
}

// head via MFMA: block = 64 rows, 4 waves x 32-col strips, 4 row-groups/wave.
__global__ void L384_headm(const u16* X, const u16* Wt, const float* Wb, float* out) {
  __shared__ float red[4][64];
  const int t = threadIdx.x;
  const int w = t >> 6;
  const int l = t & 63;
  const int row0 = blockIdx.x * 64;
  const int lr = l & 15;
  const int kg = l >> 4;
  f32x4 acc[4][2];
#pragma unroll
  for (int rg = 0; rg < 4; ++rg) {
    acc[rg][0] = (f32x4){0.f, 0.f, 0.f, 0.f};
    acc[rg][1] = (f32x4){0.f, 0.f, 0.f, 0.f};
  }
  const u16* arow[4];
#pragma unroll
  for (int rg = 0; rg < 4; ++rg) {
    int r = row0 + rg * 16 + lr;
    if (r >= N2) r = N2 - 1;
    arow[rg] = X + (size_t)r * 320 + kg * 8;
  }
  const u16* b0row = Wt + (size_t)(w * 32 + lr) * 320 + kg * 8;
  const u16* b1row = Wt + (size_t)(w * 32 + 16 + lr) * 320 + kg * 8;
#pragma unroll
  for (int k0 = 0; k0 < 320; k0 += 32) {
    union { bf16x8 v; uint4 q; } af[4], b0, b1;
#pragma unroll
    for (int rg = 0; rg < 4; ++rg) af[rg].q = *(const uint4*)(arow[rg] + k0);
    b0.q = *(const uint4*)(b0row + k0);
    b1.q = *(const uint4*)(b1row + k0);
#pragma unroll
    for (int rg = 0; rg < 4; ++rg) {
      acc[rg][0] = __builtin_amdgcn_mfma_f32_16x16x32_bf16(af[rg].v, b0.v,
                                                           acc[rg][0], 0, 0, 0);
      acc[rg][1] = __builtin_amdgcn_mfma_f32_16x16x32_bf16(af[rg].v, b1.v,
                                                           acc[rg][1], 0, 0, 0);
    }
  }
  const int col0 = w * 32 + lr;
  const int col1 = col0 + 16;
  float wb0 = Wb[col0], wb1 = Wb[col1];
  float z0[4][4], z1[4][4];
#pragma unroll
  for (int rg = 0; rg < 4; ++rg) {
    float pssq[4];
#pragma unroll
    for (int r = 0; r < 4; ++r) {
      z0[rg][r] = fmaxf(acc[rg][0][r] + wb0, 0.f);
      z1[rg][r] = fmaxf(acc[rg][1][r] + wb1, 0.f);
      pssq[r] = z0[rg][r] * z0[rg][r] + z1[rg][r] * z1[rg][r];
    }
#pragma unroll
    for (int off = 8; off; off >>= 1) {
#pragma unroll
      for (int r = 0; r < 4; ++r) pssq[r] += __shfl_xor(pssq[r], off);
    }
    if (lr == 0) {
#pragma unroll
      for (int r = 0; r < 4; ++r) red[w][rg * 16 + kg * 4 + r] = pssq[r];
    }
  }
  __syncthreads();
#pragma unroll
  for (int rg = 0; rg < 4; ++rg) {
#pragma unroll
    for (int r = 0; r < 4; ++r) {
      int lrow = rg * 16 + kg * 4 + r;
      int grow = row0 + lrow;
      if (grow < N2) {
        float ssq = red[0][lrow] + red[1][lrow] + red[2][lrow] + red[3][lrow];
        float inv = (ssq > 0.f) ? rsqrtf(ssq) : 0.f;
        float* op = out + (size_t)grow * 128;
        op[col0] = z0[rg][r] * inv;
        op[col1] = z1[rg][r] * inv;
      }
    }
  }
}

extern "C" void kernel_launch(void* const* d_in, const int* in_sizes, int n_in,
                              void* d_out, int out_size, void* d_ws, size_t ws_size,
                              hipStream_t stream) {
  (void)in_sizes; (void)n_in; (void)out_size; (void)ws_size;
  const float* h_src_user = (const float*)d_in[0];
  const float* h_src_item = (const float*)d_in[1];
  const float* h_dst_user = (const float*)d_in[2];
  const float* h_dst_item = (const float*)d_in[3];
  const int* u2i_src = (const int*)d_in[4];
  const int* u2i_dst = (const int*)d_in[5];
  const int* i2u_src = (const int*)d_in[6];
  const int* i2u_dst = (const int*)d_in[7];
  const float* fc_w = (const float*)d_in[8];
  const float* attn_l = (const float*)d_in[9];
  const float* attn_r = (const float*)d_in[10];
  const float* gat_bias = (const float*)d_in[11];
  const float* W_w = (const float*)d_in[12];
  const float* W_b = (const float*)d_in[13];
  float* out = (float*)d_out;  // f32 [2NN][128] = [z_user; z_item]

  float* el = (float*)d_ws;                     // N2*4
  float* er = el + (size_t)N2 * 4;              // N2*4
  float* w_r = er + (size_t)N2 * 4;             // 1024
  u16* wlB = (u16*)(w_r + 1024);                // 16*256
  float* alpha = (float*)(wlB + 16 * 256);      // E2*4 (fallback only)
  u16* fs = (u16*)(alpha + (size_t)E2 * 4);     // N2*256 bf16
  u16* X = fs + (size_t)N2 * 256;               // N2*320 bf16
  u16* Bt = X + (size_t)N2 * 320;               // 256*256
  u16* Wt = Bt + 256 * 256;                     // 128*320
  int* indptr = (int*)(Wt + 128 * 320);         // N2+1 (+pad)
  int* cur = indptr + (N2 + 4);                 // N2
  int* csr = cur + N2;                          // E2

  // constants + prep (dst-only)
  L384_const<<<385, 256, 0, stream>>>(fc_w, attn_l, attn_r, W_w, w_r, wlB, Bt, Wt);
  L384_prep<<<25000, 256, 0, stream>>>(h_dst_user, h_dst_item, w_r, X, er);

  // merged CSR build (2NN nodes, 2EE edges)
  L384_zero<<<391, 256, 0, stream>>>(cur, N2);
  L384_hist<<<3907, 256, 0, stream>>>(i2u_dst, u2i_dst, cur);
  L384_scan<<<1, 1024, 0, stream>>>(cur, indptr, cur, N2);
  L384_fill<<<3907, 256, 0, stream>>>(i2u_src, i2u_dst, u2i_src, u2i_dst, cur, csr);
  L384_sort<<<391, 256, 0, stream>>>(indptr, csr, N2);

  // merged compute
  L384_gemm<<<782, 512, 0, stream>>>(h_src_user, h_src_item, Bt, wlB, fs, el);
  L384_aggx<<<25000, 256, 0, stream>>>(indptr, csr, el, er, fs, gat_bias, alpha, X);
  L384_headm<<<1563, 256, 0, stream>>>(X, Wt, W_b, out);
}

// Round 38
// 386.564 us; speedup vs baseline: 1.5371x; 1.5371x over previous
//
#include <hip/hip_runtime.h>

#define NN 50000
#define N2 100000
#define EE 500000
#define E2 1000000

typedef unsigned short u16;
typedef unsigned int u32;

typedef __attribute__((ext_vector_type(8))) __bf16 bf16x8;
typedef __attribute__((ext_vector_type(4))) float f32x4;

__device__ __forceinline__ float4 ld4(const float* p) { return *(const float4*)p; }

// round-to-nearest-even f32 -> bf16 bits
__device__ __forceinline__ u16 f2bf(float f) {
  u32 u = __float_as_uint(f);
  u += 0x7FFFu + ((u >> 16) & 1u);
  return (u16)(u >> 16);
}

// HW packed convert: low16 = bf16(lo), high16 = bf16(hi) (RNE)
__device__ __forceinline__ u32 cvtpk(float lo, float hi) {
  u32 r;
  asm("v_cvt_pk_bf16_f32 %0, %1, %2" : "=v"(r) : "v"(lo), "v"(hi));
  return r;
}

// fused constants kernel
__global__ void L384_const(const float* fc_w, const float* attn_l,
                           const float* attn_r, const float* Ww, float* w_r,
                           u16* wlB, u16* Bt, u16* Wt) {
  const int b = blockIdx.x;
  const int t = threadIdx.x;
  if (b < 256) {
    Bt[b * 256 + t] = f2bf(fc_w[(size_t)t * 256 + b]);
  } else if (b == 256) {
    for (int h = 0; h < 4; ++h) {
      float sl = 0.f, sr = 0.f;
      for (int d = 0; d < 64; ++d) {
        float f = fc_w[t * 256 + h * 64 + d];
        sl += f * attn_l[h * 64 + d];
        sr += f * attn_r[h * 64 + d];
      }
      w_r[t * 4 + h] = sr;
      wlB[h * 256 + t] = f2bf(sl);
    }
    for (int h = 4; h < 16; ++h) wlB[h * 256 + t] = 0;
  } else {
    int n = b - 257;
    for (int k = t; k < 320; k += 256)
      Wt[(size_t)n * 320 + k] = f2bf(Ww[(size_t)k * 128 + n]);
  }
}

// prep over 2NN dst rows only: X[r][64..320) = bf16(dst feats); er = dst . w_r
__global__ void L384_prep(const float* Du, const float* Di, const float* w_r_,
                          u16* X, float* er) {
  const int r = blockIdx.x * 4 + (threadIdx.x >> 6);
  const int lane = threadIdx.x & 63;
  if (r >= N2) return;
  const float* src = (r < NN) ? Du + (size_t)r * 256 : Di + (size_t)(r - NN) * 256;
  float4 xv = ld4(src + lane * 4);
  uint2 pk = make_uint2(cvtpk(xv.x, xv.y), cvtpk(xv.z, xv.w));
  *(uint2*)(X + (size_t)r * 320 + 64 + lane * 4) = pk;
  const float* wr = w_r_ + lane * 16;
  float4 w0 = ld4(wr), w1 = ld4(wr + 4), w2 = ld4(wr + 8), w3 = ld4(wr + 12);
  float a0 = xv.x * w0.x + xv.y * w1.x + xv.z * w2.x + xv.w * w3.x;
  float a1 = xv.x * w0.y + xv.y * w1.y + xv.z * w2.y + xv.w * w3.y;
  float a2 = xv.x * w0.z + xv.y * w1.z + xv.z * w2.z + xv.w * w3.z;
  float a3 = xv.x * w0.w + xv.y * w1.w + xv.z * w2.w + xv.w * w3.w;
  for (int off = 32; off; off >>= 1) {
    a0 += __shfl_xor(a0, off);
    a1 += __shfl_xor(a1, off);
    a2 += __shfl_xor(a2, off);
    a3 += __shfl_xor(a3, off);
  }
  if (lane == 0) {
    float* op = er + (size_t)r * 4;
    op[0] = a0; op[1] = a1; op[2] = a2; op[3] = a3;
  }
}

// gemm: fs = bf16(Asrc) @ fc_w; el = Asrc @ w_l (wlB MFMA, once per block).
__global__ __launch_bounds__(512) void L384_gemm(const float* Au, const float* Ai,
                                                 const u16* Bt, const u16* wlB,
                                                 u16* C, float* el) {
  __shared__ u16 bs[64][264];
  const int t = threadIdx.x;
  const int w = t >> 6;
  const int l = t & 63;
  const int lr = l & 15;
  const int kg = l >> 4;
  const int row0 = blockIdx.x * 128;

  const int row = row0 + w * 16 + lr;
  const int rr = (row < N2) ? row : (N2 - 1);
  const float* arow =
      ((rr < NN) ? Au + (size_t)rr * 256 : Ai + (size_t)(rr - NN) * 256) + kg * 8;
  uint4 a[8];
#pragma unroll
  for (int ks = 0; ks < 8; ++ks) {
    float4 f0 = ld4(arow + ks * 32);
    float4 f1 = ld4(arow + ks * 32 + 4);
    a[ks] = make_uint4(cvtpk(f0.x, f0.y), cvtpk(f0.z, f0.w), cvtpk(f1.x, f1.y),
                       cvtpk(f1.z, f1.w));
  }

  {
    f32x4 eacc = {0.f, 0.f, 0.f, 0.f};
    const u16* wl = wlB + lr * 256 + kg * 8;
#pragma unroll
    for (int ks = 0; ks < 8; ++ks) {
      union { bf16x8 v; uint4 q; } af, wf;
      af.q = a[ks];
      wf.q = *(const uint4*)(wl + ks * 32);
      eacc = __builtin_amdgcn_mfma_f32_16x16x32_bf16(af.v, wf.v, eacc, 0, 0, 0);
    }
    if (lr < 4) {
#pragma unroll
      for (int r = 0; r < 4; ++r) {
        int grow = row0 + w * 16 + kg * 4 + r;
        if (grow < N2) el[(size_t)grow * 4 + lr] = eacc[r];
      }
    }
  }

  for (int strip = 0; strip < 4; ++strip) {
    __syncthreads();
    {
      const int brow = t >> 3;
      const int bc = (t & 7) * 32;
      const uint4* s = (const uint4*)(Bt + (size_t)(strip * 64 + brow) * 256 + bc);
      uint4* d = (uint4*)&bs[brow][bc];
      d[0] = s[0]; d[1] = s[1]; d[2] = s[2]; d[3] = s[3];
    }
    __syncthreads();

    f32x4 acc[4];
#pragma unroll
    for (int ct = 0; ct < 4; ++ct) acc[ct] = (f32x4){0.f, 0.f, 0.f, 0.f};
#pragma unroll
    for (int ks = 0; ks < 8; ++ks) {
      union { bf16x8 v; uint4 q; } af;
      af.q = a[ks];
#pragma unroll
      for (int ct = 0; ct < 4; ++ct) {
        union { bf16x8 v; uint4 q; } b;
        b.q = *(const uint4*)&bs[ct * 16 + lr][ks * 32 + kg * 8];
        acc[ct] = __builtin_amdgcn_mfma_f32_16x16x32_bf16(af.v, b.v, acc[ct], 0, 0, 0);
      }
    }

#pragma unroll
    for (int p = 0; p < 2; ++p) {
      __syncthreads();
      if ((w >> 2) == p) {
        const int lrow = (w & 3) * 16 + kg * 4;
#pragma unroll
        for (int ct = 0; ct < 4; ++ct)
#pragma unroll
          for (int r = 0; r < 4; ++r)
            bs[lrow + r][ct * 16 + lr] = f2bf(acc[ct][r]);
      }
      __syncthreads();
      const int lrow2 = t >> 3;
      const int c0 = (t & 7) * 8;
      const int grow = row0 + p * 64 + lrow2;
      if (grow < N2)
        *(uint4*)(C + (size_t)grow * 256 + strip * 64 + c0) =
            *(const uint4*)&bs[lrow2][c0];
    }
  }
}

__global__ void L384_zero(int* p, int n) {
  int i = blockIdx.x * 256 + threadIdx.x;
  if (i < n) p[i] = 0;
}
__global__ void L384_hist(const int* i2u_dst, const int* u2i_dst, int* cnt) {
  int e = blockIdx.x * 256 + threadIdx.x;
  if (e < EE) {
    int d = i2u_dst[e];
    d = ((unsigned)d < NN) ? d : 0;
    atomicAdd(&cnt[d], 1);
  } else if (e < E2) {
    int d = u2i_dst[e - EE];
    d = ((unsigned)d < NN) ? d : 0;
    atomicAdd(&cnt[NN + d], 1);
  }
}
__global__ void L384_scan1(const int* cnt, int* part, int* bsum, int n) {
  __shared__ int sh[256];
  const int t = threadIdx.x;
  const int base = blockIdx.x * 1024 + t * 4;
  int v0 = (base + 0 < n) ? cnt[base + 0] : 0;
  int v1 = (base + 1 < n) ? cnt[base + 1] : 0;
  int v2 = (base + 2 < n) ? cnt[base + 2] : 0;
  int v3 = (base + 3 < n) ? cnt[base + 3] : 0;
  int s0 = v0, s1 = s0 + v1, s2 = s1 + v2, s3 = s2 + v3;
  sh[t] = s3;
  __syncthreads();
  for (int off = 1; off < 256; off <<= 1) {
    int x = (t >= off) ? sh[t - off] : 0;
    __syncthreads();
    sh[t] += x;
    __syncthreads();
  }
  int excl = (t > 0) ? sh[t - 1] : 0;
  if (base + 0 < n) part[base + 0] = excl;
  if (base + 1 < n) part[base + 1] = excl + s0;
  if (base + 2 < n) part[base + 2] = excl + s1;
  if (base + 3 < n) part[base + 3] = excl + s2;
  if (t == 255) bsum[blockIdx.x] = sh[255];
}
__global__ void L384_scan2(int* bsum, int nb, int* indptr, int n) {
  if (threadIdx.x == 0 && blockIdx.x == 0) {
    int acc = 0;
    for (int i = 0; i < nb; ++i) {
      int c = bsum[i];
      bsum[i] = acc;
      acc += c;
    }
    indptr[n] = acc;
  }
}
__global__ void L384_scan3(int* indptr, const int* bsum, int* cur, int n) {
  int i = blockIdx.x * 256 + threadIdx.x;
  if (i < n) {
    int v = indptr[i] + bsum[i >> 10];
    indptr[i] = v;
    cur[i] = v;
  }
}
__global__ void L384_fill(const int* i2u_src, const int* i2u_dst,
                          const int* u2i_src, const int* u2i_dst,
                          int* cur, int* csr) {
  int e = blockIdx.x * 256 + threadIdx.x;
  if (e < EE) {
    int d = i2u_dst[e];
    d = ((unsigned)d < NN) ? d : 0;
    int s = i2u_src[e];
    s = ((unsigned)s < NN) ? s : 0;
    int pos = atomicAdd(&cur[d], 1);
    if ((unsigned)pos < E2) csr[pos] = NN + s;
  } else if (e < E2) {
    int d = u2i_dst[e - EE];
    d = ((unsigned)d < NN) ? d : 0;
    int s = u2i_src[e - EE];
    s = ((unsigned)s < NN) ? s : 0;
    int pos = atomicAdd(&cur[NN + d], 1);
    if ((unsigned)pos < E2) csr[pos] = s;
  }
}
// LDS-staged per-node sort: block covers 256 nodes' contiguous CSR range.
__global__ void L384_sort(const int* indptr, int* csr, int n) {
  __shared__ int buf[5120];
  const int t = threadIdx.x;
  const int node0 = blockIdx.x * 256;
  const int nEnd = (node0 + 256 < n) ? (node0 + 256) : n;
  if (node0 >= n) return;
  const int segL = indptr[node0];
  const int segR = indptr[nEnd];
  const int len = segR - segL;
  if (len <= 5120) {
    for (int i = t; i < len; i += 256) buf[i] = csr[segL + i];
    __syncthreads();
    const int node = node0 + t;
    if (node < n) {
      int p0 = indptr[node] - segL;
      int p1 = indptr[node + 1] - segL;
      for (int a = p0 + 1; a < p1; ++a) {
        int v = buf[a];
        int b = a - 1;
        while (b >= p0 && buf[b] > v) {
          buf[b + 1] = buf[b];
          --b;
        }
        buf[b + 1] = v;
      }
    }
    __syncthreads();
    for (int i = t; i < len; i += 256) csr[segL + i] = buf[i];
  } else {
    const int node = node0 + t;
    if (node < n) {
      int p0 = indptr[node], p1 = indptr[node + 1];
      for (int a = p0 + 1; a < p1; ++a) {
        int v = csr[a];
        int b = a - 1;
        while (b >= p0 && csr[b] > v) {
          csr[b + 1] = csr[b];
          --b;
        }
        csr[b + 1] = v;
      }
    }
  }
}

// fused edge-softmax + aggregation: one wave per dst node.
// aL layout [slot][edge][head]: conflict-free broadcast reads in phase B.
__global__ void L384_aggx(const int* indptr, const int* csr, const float* el,
                          const float* er, const u16* fs, const float* bias,
                          float* alphaG, u16* X) {
  __shared__ float aL[4][64][4];
  __shared__ int sL[4][64];
  const int slot = threadIdx.x >> 6;
  const int wid = blockIdx.x * 4 + slot;
  const int lane = threadIdx.x & 63;
  if (wid >= N2) return;
  const int p0 = indptr[wid];
  const int deg = indptr[wid + 1] - p0;
  const int h = lane >> 4;
  const int c = lane & 15;
  float4 er4 = ld4(er + (size_t)wid * 4);

  const bool small = (deg <= 64);
  if (small) {
    float4 ex = {0.f, 0.f, 0.f, 0.f};
    int s = 0;
    if (lane < deg) {
      s = csr[p0 + lane];
      s = ((unsigned)s < N2) ? s : 0;
      float4 ev = ld4(el + (size_t)s * 4);
      float e0 = ev.x + er4.x; e0 = (e0 >= 0.f) ? e0 : 0.2f * e0;
      float e1 = ev.y + er4.y; e1 = (e1 >= 0.f) ? e1 : 0.2f * e1;
      float e2 = ev.z + er4.z; e2 = (e2 >= 0.f) ? e2 : 0.2f * e2;
      float e3 = ev.w + er4.w; e3 = (e3 >= 0.f) ? e3 : 0.2f * e3;
      ex = make_float4(__expf(e0), __expf(e1), __expf(e2), __expf(e3));
    }
    float d0 = ex.x, d1 = ex.y, d2 = ex.z, d3 = ex.w;
    for (int off = 32; off; off >>= 1) {
      d0 += __shfl_xor(d0, off);
      d1 += __shfl_xor(d1, off);
      d2 += __shfl_xor(d2, off);
      d3 += __shfl_xor(d3, off);
    }
    if (lane < deg) {
      float4 o = make_float4(ex.x / d0, ex.y / d1, ex.z / d2, ex.w / d3);
      *(float4*)&aL[slot][lane][0] = o;
      sL[slot][lane] = s;
    }
  } else if (deg > 0) {
    float d0 = 0.f, d1 = 0.f, d2 = 0.f, d3 = 0.f;
    for (int i = lane; i < deg; i += 64) {
      int s = csr[p0 + i];
      s = ((unsigned)s < N2) ? s : 0;
      float4 ev = ld4(el + (size_t)s * 4);
      float e0 = ev.x + er4.x; e0 = (e0 >= 0.f) ? e0 : 0.2f * e0;
      float e1 = ev.y + er4.y; e1 = (e1 >= 0.f) ? e1 : 0.2f * e1;
      float e2 = ev.z + er4.z; e2 = (e2 >= 0.f) ? e2 : 0.2f * e2;
      float e3 = ev.w + er4.w; e3 = (e3 >= 0.f) ? e3 : 0.2f * e3;
      float4 ex = make_float4(__expf(e0), __expf(e1), __expf(e2), __expf(e3));
      *(float4*)(alphaG + (size_t)(p0 + i) * 4) = ex;
      d0 += ex.x; d1 += ex.y; d2 += ex.z; d3 += ex.w;
    }
    for (int off = 32; off; off >>= 1) {
      d0 += __shfl_xor(d0, off);
      d1 += __shfl_xor(d1, off);
      d2 += __shfl_xor(d2, off);
      d3 += __shfl_xor(d3, off);
    }
    float i0 = 1.f / d0, i1 = 1.f / d1, i2 = 1.f / d2, i3 = 1.f / d3;
    for (int i = lane; i < deg; i += 64) {
      float4 ex = *(const float4*)(alphaG + (size_t)(p0 + i) * 4);
      *(float4*)(alphaG + (size_t)(p0 + i) * 4) =
          make_float4(ex.x * i0, ex.y * i1, ex.z * i2, ex.w * i3);
    }
  }

  float ax = 0.f, ay = 0.f, az = 0.f, aw = 0.f;
  int i = 0;
  for (; i + 4 <= deg; i += 4) {
    int s0, s1, s2, s3;
    float a0, a1, a2, a3;
    if (small) {
      s0 = sL[slot][i + 0]; s1 = sL[slot][i + 1];
      s2 = sL[slot][i + 2]; s3 = sL[slot][i + 3];
      a0 = aL[slot][i + 0][h]; a1 = aL[slot][i + 1][h];
      a2 = aL[slot][i + 2][h]; a3 = aL[slot][i + 3][h];
    } else {
      s0 = csr[p0 + i + 0]; s0 = ((unsigned)s0 < N2) ? s0 : 0;
      s1 = csr[p0 + i + 1]; s1 = ((unsigned)s1 < N2) ? s1 : 0;
      s2 = csr[p0 + i + 2]; s2 = ((unsigned)s2 < N2) ? s2 : 0;
      s3 = csr[p0 + i + 3]; s3 = ((unsigned)s3 < N2) ? s3 : 0;
      a0 = alphaG[(size_t)(p0 + i + 0) * 4 + h];
      a1 = alphaG[(size_t)(p0 + i + 1) * 4 + h];
      a2 = alphaG[(size_t)(p0 + i + 2) * 4 + h];
      a3 = alphaG[(size_t)(p0 + i + 3) * 4 + h];
    }
    uint2 q0 = *(const uint2*)(fs + (size_t)s0 * 256 + lane * 4);
    uint2 q1 = *(const uint2*)(fs + (size_t)s1 * 256 + lane * 4);
    uint2 q2 = *(const uint2*)(fs + (size_t)s2 * 256 + lane * 4);
    uint2 q3 = *(const uint2*)(fs + (size_t)s3 * 256 + lane * 4);
    ax += a0 * __uint_as_float(q0.x << 16);
    ay += a0 * __uint_as_float(q0.x & 0xffff0000u);
    az += a0 * __uint_as_float(q0.y << 16);
    aw += a0 * __uint_as_float(q0.y & 0xffff0000u);
    ax += a1 * __uint_as_float(q1.x << 16);
    ay += a1 * __uint_as_float(q1.x & 0xffff0000u);
    az += a1 * __uint_as_float(q1.y << 16);
    aw += a1 * __uint_as_float(q1.y & 0xffff0000u);
    ax += a2 * __uint_as_float(q2.x << 16);
    ay += a2 * __uint_as_float(q2.x & 0xffff0000u);
    az += a2 * __uint_as_float(q2.y << 16);
    aw += a2 * __uint_as_float(q2.y & 0xffff0000u);
    ax += a3 * __uint_as_float(q3.x << 16);
    ay += a3 * __uint_as_float(q3.x & 0xffff0000u);
    az += a3 * __uint_as_float(q3.y << 16);
    aw += a3 * __uint_as_float(q3.y & 0xffff0000u);
  }
  for (; i < deg; ++i) {
    int s0;
    float a0;
    if (small) {
      s0 = sL[slot][i];
      a0 = aL[slot][i][h];
    } else {
      s0 = csr[p0 + i]; s0 = ((unsigned)s0 < N2) ? s0 : 0;
      a0 = alphaG[(size_t)(p0 + i) * 4 + h];
    }
    uint2 q0 = *(const uint2*)(fs + (size_t)s0 * 256 + lane * 4);
    ax += a0 * __uint_as_float(q0.x << 16);
    ay += a0 * __uint_as_float(q0.x & 0xffff0000u);
    az += a0 * __uint_as_float(q0.y << 16);
    aw += a0 * __uint_as_float(q0.y & 0xffff0000u);
  }
  const float* bp = bias + lane * 4;
  float ox = ax + bp[0];
  float oy = ay + bp[1];
  float oz = az + bp[2];
  float ow = aw + bp[3];
  for (int off = 16; off <= 32; off <<= 1) {
    ox += __shfl_xor(ox, off);
    oy += __shfl_xor(oy, off);
    oz += __shfl_xor(oz, off);
    ow += __shfl_xor(ow, off);
  }
  if (h == 0) {
    uint2 pk = make_uint2(cvtpk(ox * 0.25f, oy * 0.25f), cvtpk(oz * 0.25f, ow * 0.25f));
    *(uint2*)(X + (size_t)wid * 320 + 4 * c) = pk;
  }
}

// head via MFMA: block = 64 rows, 4 waves x 32-col strips, 4 row-groups/wave.
__global__ void L384_headm(const u16* X, const u16* Wt, const float* Wb, float* out) {
  __shared__ float red[4][64];
  const int t = threadIdx.x;
  const int w = t >> 6;
  const int l = t & 63;
  const int row0 = blockIdx.x * 64;
  const int lr = l & 15;
  const int kg = l >> 4;
  f32x4 acc[4][2];
#pragma unroll
  for (int rg = 0; rg < 4; ++rg) {
    acc[rg][0] = (f32x4){0.f, 0.f, 0.f, 0.f};
    acc[rg][1] = (f32x4){0.f, 0.f, 0.f, 0.f};
  }
  const u16* arow[4];
#pragma unroll
  for (int rg = 0; rg < 4; ++rg) {
    int r = row0 + rg * 16 + lr;
    if (r >= N2) r = N2 - 1;
    arow[rg] = X + (size_t)r * 320 + kg * 8;
  }
  const u16* b0row = Wt + (size_t)(w * 32 + lr) * 320 + kg * 8;
  const u16* b1row = Wt + (size_t)(w * 32 + 16 + lr) * 320 + kg * 8;
#pragma unroll
  for (int k0 = 0; k0 < 320; k0 += 32) {
    union { bf16x8 v; uint4 q; } af[4], b0, b1;
#pragma unroll
    for (int rg = 0; rg < 4; ++rg) af[rg].q = *(const uint4*)(arow[rg] + k0);
    b0.q = *(const uint4*)(b0row + k0);
    b1.q = *(const uint4*)(b1row + k0);
#pragma unroll
    for (int rg = 0; rg < 4; ++rg) {
      acc[rg][0] = __builtin_amdgcn_mfma_f32_16x16x32_bf16(af[rg].v, b0.v,
                                                           acc[rg][0], 0, 0, 0);
      acc[rg][1] = __builtin_amdgcn_mfma_f32_16x16x32_bf16(af[rg].v, b1.v,
                                                           acc[rg][1], 0, 0, 0);
    }
  }
  const int col0 = w * 32 + lr;
  const int col1 = col0 + 16;
  float wb0 = Wb[col0], wb1 = Wb[col1];
  float z0[4][4], z1[4][4];
#pragma unroll
  for (int rg = 0; rg < 4; ++rg) {
    float pssq[4];
#pragma unroll
    for (int r = 0; r < 4; ++r) {
      z0[rg][r] = fmaxf(acc[rg][0][r] + wb0, 0.f);
      z1[rg][r] = fmaxf(acc[rg][1][r] + wb1, 0.f);
      pssq[r] = z0[rg][r] * z0[rg][r] + z1[rg][r] * z1[rg][r];
    }
#pragma unroll
    for (int off = 8; off; off >>= 1) {
#pragma unroll
      for (int r = 0; r < 4; ++r) pssq[r] += __shfl_xor(pssq[r], off);
    }
    if (lr == 0) {
#pragma unroll
      for (int r = 0; r < 4; ++r) red[w][rg * 16 + kg * 4 + r] = pssq[r];
    }
  }
  __syncthreads();
#pragma unroll
  for (int rg = 0; rg < 4; ++rg) {
#pragma unroll
    for (int r = 0; r < 4; ++r) {
      int lrow = rg * 16 + kg * 4 + r;
      int grow = row0 + lrow;
      if (grow < N2) {
        float ssq = red[0][lrow] + red[1][lrow] + red[2][lrow] + red[3][lrow];
        float inv = (ssq > 0.f) ? rsqrtf(ssq) : 0.f;
        float* op = out + (size_t)grow * 128;
        op[col0] = z0[rg][r] * inv;
        op[col1] = z1[rg][r] * inv;
      }
    }
  }
}

extern "C" void kernel_launch(void* const* d_in, const int* in_sizes, int n_in,
                              void* d_out, int out_size, void* d_ws, size_t ws_size,
                              hipStream_t stream) {
  (void)in_sizes; (void)n_in; (void)out_size; (void)ws_size;
  const float* h_src_user = (const float*)d_in[0];
  const float* h_src_item = (const float*)d_in[1];
  const float* h_dst_user = (const float*)d_in[2];
  const float* h_dst_item = (const float*)d_in[3];
  const int* u2i_src = (const int*)d_in[4];
  const int* u2i_dst = (const int*)d_in[5];
  const int* i2u_src = (const int*)d_in[6];
  const int* i2u_dst = (const int*)d_in[7];
  const float* fc_w = (const float*)d_in[8];
  const float* attn_l = (const float*)d_in[9];
  const float* attn_r = (const float*)d_in[10];
  const float* gat_bias = (const float*)d_in[11];
  const float* W_w = (const float*)d_in[12];
  const float* W_b = (const float*)d_in[13];
  float* out = (float*)d_out;  // f32 [2NN][128] = [z_user; z_item]

  float* el = (float*)d_ws;                     // N2*4
  float* er = el + (size_t)N2 * 4;              // N2*4
  float* w_r = er + (size_t)N2 * 4;             // 1024
  u16* wlB = (u16*)(w_r + 1024);                // 16*256
  float* alpha = (float*)(wlB + 16 * 256);      // E2*4 (fallback only)
  u16* fs = (u16*)(alpha + (size_t)E2 * 4);     // N2*256 bf16
  u16* X = fs + (size_t)N2 * 256;               // N2*320 bf16
  u16* Bt = X + (size_t)N2 * 320;               // 256*256
  u16* Wt = Bt + 256 * 256;                     // 128*320
  int* indptr = (int*)(Wt + 128 * 320);         // N2+1 (+pad)
  int* cur = indptr + (N2 + 4);                 // N2
  int* csr = cur + N2;                          // E2
  int* bsum = csr + E2;                         // 128

  // constants + prep (dst-only)
  L384_const<<<385, 256, 0, stream>>>(fc_w, attn_l, attn_r, W_w, w_r, wlB, Bt, Wt);
  L384_prep<<<25000, 256, 0, stream>>>(h_dst_user, h_dst_item, w_r, X, er);

  // merged CSR build (2NN nodes, 2EE edges)
  L384_zero<<<391, 256, 0, stream>>>(cur, N2);
  L384_hist<<<3907, 256, 0, stream>>>(i2u_dst, u2i_dst, cur);
  L384_scan1<<<98, 256, 0, stream>>>(cur, indptr, bsum, N2);
  L384_scan2<<<1, 1, 0, stream>>>(bsum, 98, indptr, N2);
  L384_scan3<<<391, 256, 0, stream>>>(indptr, bsum, cur, N2);
  L384_fill<<<3907, 256, 0, stream>>>(i2u_src, i2u_dst, u2i_src, u2i_dst, cur, csr);
  L384_sort<<<391, 256, 0, stream>>>(indptr, csr, N2);

  // merged compute
  L384_gemm<<<782, 512, 0, stream>>>(h_src_user, h_src_item, Bt, wlB, fs, el);
  L384_aggx<<<25000, 256, 0, stream>>>(indptr, csr, el, er, fs, gat_bias, alpha, X);
  L384_headm<<<1563, 256, 0, stream>>>(X, Wt, W_b, out);
}

// Round 39
// 364.096 us; speedup vs baseline: 1.6319x; 1.0617x over previous
//
#include <hip/hip_runtime.h>

#define NN 50000
#define N2 100000
#define EE 500000
#define E2 1000000

typedef unsigned short u16;
typedef unsigned int u32;

typedef __attribute__((ext_vector_type(8))) __bf16 bf16x8;
typedef __attribute__((ext_vector_type(4))) float f32x4;

__device__ __forceinline__ float4 ld4(const float* p) { return *(const float4*)p; }

// round-to-nearest-even f32 -> bf16 bits
__device__ __forceinline__ u16 f2bf(float f) {
  u32 u = __float_as_uint(f);
  u += 0x7FFFu + ((u >> 16) & 1u);
  return (u16)(u >> 16);
}

// HW packed convert: low16 = bf16(lo), high16 = bf16(hi) (RNE)
__device__ __forceinline__ u32 cvtpk(float lo, float hi) {
  u32 r;
  asm("v_cvt_pk_bf16_f32 %0, %1, %2" : "=v"(r) : "v"(lo), "v"(hi));
  return r;
}

// fused constants + cur-zero kernel:
//  blocks 0..255   : Bt transpose; 256: w_r/wlB; 257..384: Wt transpose
//  blocks 385..775 : cur[i] = 0
__global__ void L384_const(const float* fc_w, const float* attn_l,
                           const float* attn_r, const float* Ww, float* w_r,
                           u16* wlB, u16* Bt, u16* Wt, int* cur) {
  const int b = blockIdx.x;
  const int t = threadIdx.x;
  if (b < 256) {
    Bt[b * 256 + t] = f2bf(fc_w[(size_t)t * 256 + b]);
  } else if (b == 256) {
    for (int h = 0; h < 4; ++h) {
      float sl = 0.f, sr = 0.f;
      for (int d = 0; d < 64; ++d) {
        float f = fc_w[t * 256 + h * 64 + d];
        sl += f * attn_l[h * 64 + d];
        sr += f * attn_r[h * 64 + d];
      }
      w_r[t * 4 + h] = sr;
      wlB[h * 256 + t] = f2bf(sl);
    }
    for (int h = 4; h < 16; ++h) wlB[h * 256 + t] = 0;
  } else if (b < 385) {
    int n = b - 257;
    for (int k = t; k < 320; k += 256)
      Wt[(size_t)n * 320 + k] = f2bf(Ww[(size_t)k * 128 + n]);
  } else {
    int i = (b - 385) * 256 + t;
    if (i < N2) cur[i] = 0;
  }
}

// fused prep + hist:
//  blocks 0..24999     : X staging + er for dst rows
//  blocks 25000..28906 : degree histogram (atomics into cur)
__global__ void L384_prep(const float* Du, const float* Di, const float* w_r_,
                          u16* X, float* er, const int* i2u_dst,
                          const int* u2i_dst, int* cnt) {
  const int b = blockIdx.x;
  if (b >= 25000) {
    int e = (b - 25000) * 256 + threadIdx.x;
    if (e < EE) {
      int d = i2u_dst[e];
      d = ((unsigned)d < NN) ? d : 0;
      atomicAdd(&cnt[d], 1);
    } else if (e < E2) {
      int d = u2i_dst[e - EE];
      d = ((unsigned)d < NN) ? d : 0;
      atomicAdd(&cnt[NN + d], 1);
    }
    return;
  }
  const int r = b * 4 + (threadIdx.x >> 6);
  const int lane = threadIdx.x & 63;
  if (r >= N2) return;
  const float* src = (r < NN) ? Du + (size_t)r * 256 : Di + (size_t)(r - NN) * 256;
  float4 xv = ld4(src + lane * 4);
  uint2 pk = make_uint2(cvtpk(xv.x, xv.y), cvtpk(xv.z, xv.w));
  *(uint2*)(X + (size_t)r * 320 + 64 + lane * 4) = pk;
  const float* wr = w_r_ + lane * 16;
  float4 w0 = ld4(wr), w1 = ld4(wr + 4), w2 = ld4(wr + 8), w3 = ld4(wr + 12);
  float a0 = xv.x * w0.x + xv.y * w1.x + xv.z * w2.x + xv.w * w3.x;
  float a1 = xv.x * w0.y + xv.y * w1.y + xv.z * w2.y + xv.w * w3.y;
  float a2 = xv.x * w0.z + xv.y * w1.z + xv.z * w2.z + xv.w * w3.z;
  float a3 = xv.x * w0.w + xv.y * w1.w + xv.z * w2.w + xv.w * w3.w;
  for (int off = 32; off; off >>= 1) {
    a0 += __shfl_xor(a0, off);
    a1 += __shfl_xor(a1, off);
    a2 += __shfl_xor(a2, off);
    a3 += __shfl_xor(a3, off);
  }
  if (lane == 0) {
    float* op = er + (size_t)r * 4;
    op[0] = a0; op[1] = a1; op[2] = a2; op[3] = a3;
  }
}

__global__ void L384_scan1(const int* cnt, int* part, int* bsum, int n) {
  __shared__ int sh[256];
  const int t = threadIdx.x;
  const int base = blockIdx.x * 1024 + t * 4;
  int v0 = (base + 0 < n) ? cnt[base + 0] : 0;
  int v1 = (base + 1 < n) ? cnt[base + 1] : 0;
  int v2 = (base + 2 < n) ? cnt[base + 2] : 0;
  int v3 = (base + 3 < n) ? cnt[base + 3] : 0;
  int s0 = v0, s1 = s0 + v1, s2 = s1 + v2, s3 = s2 + v3;
  sh[t] = s3;
  __syncthreads();
  for (int off = 1; off < 256; off <<= 1) {
    int x = (t >= off) ? sh[t - off] : 0;
    __syncthreads();
    sh[t] += x;
    __syncthreads();
  }
  int excl = (t > 0) ? sh[t - 1] : 0;
  if (base + 0 < n) part[base + 0] = excl;
  if (base + 1 < n) part[base + 1] = excl + s0;
  if (base + 2 < n) part[base + 2] = excl + s1;
  if (base + 3 < n) part[base + 3] = excl + s2;
  if (t == 255) bsum[blockIdx.x] = sh[255];
}
// fused scan2+scan3: per-block replicated 98-entry bsum prefix (cheap),
// then distribute. Block 390 also writes indptr[n] = total.
__global__ void L384_scan23(int* indptr, const int* bsum, int* cur, int nb, int n) {
  __shared__ int pre[128];
  const int t = threadIdx.x;
  if (t == 0) {
    int acc = 0;
    for (int i = 0; i < nb; ++i) {
      pre[i] = acc;
      acc += bsum[i];
    }
    pre[nb] = acc;
  }
  __syncthreads();
  int i = blockIdx.x * 256 + t;
  if (i < n) {
    int v = indptr[i] + pre[i >> 10];
    indptr[i] = v;
    cur[i] = v;
  }
  if (blockIdx.x == 0 && t == 0) indptr[n] = pre[nb];
}

// fused gemm + fill:
//  blocks 0..781    : fs = bf16(Asrc) @ fc_w; el = Asrc @ w_l (MFMA)
//  blocks 782..2735 : CSR fill (atomic position + scattered write)
__global__ __launch_bounds__(512) void L384_gemm(const float* Au, const float* Ai,
                                                 const u16* Bt, const u16* wlB,
                                                 u16* C, float* el,
                                                 const int* i2u_src, const int* i2u_dst,
                                                 const int* u2i_src, const int* u2i_dst,
                                                 int* cur, int* csr) {
  __shared__ u16 bs[64][264];
  const int t = threadIdx.x;
  if (blockIdx.x >= 782) {
    int e = (blockIdx.x - 782) * 512 + t;
    if (e < EE) {
      int d = i2u_dst[e];
      d = ((unsigned)d < NN) ? d : 0;
      int s = i2u_src[e];
      s = ((unsigned)s < NN) ? s : 0;
      int pos = atomicAdd(&cur[d], 1);
      if ((unsigned)pos < E2) csr[pos] = NN + s;
    } else if (e < E2) {
      int d = u2i_dst[e - EE];
      d = ((unsigned)d < NN) ? d : 0;
      int s = u2i_src[e - EE];
      s = ((unsigned)s < NN) ? s : 0;
      int pos = atomicAdd(&cur[NN + d], 1);
      if ((unsigned)pos < E2) csr[pos] = s;
    }
    return;
  }
  const int w = t >> 6;
  const int l = t & 63;
  const int lr = l & 15;
  const int kg = l >> 4;
  const int row0 = blockIdx.x * 128;

  const int row = row0 + w * 16 + lr;
  const int rr = (row < N2) ? row : (N2 - 1);
  const float* arow =
      ((rr < NN) ? Au + (size_t)rr * 256 : Ai + (size_t)(rr - NN) * 256) + kg * 8;
  uint4 a[8];
#pragma unroll
  for (int ks = 0; ks < 8; ++ks) {
    float4 f0 = ld4(arow + ks * 32);
    float4 f1 = ld4(arow + ks * 32 + 4);
    a[ks] = make_uint4(cvtpk(f0.x, f0.y), cvtpk(f0.z, f0.w), cvtpk(f1.x, f1.y),
                       cvtpk(f1.z, f1.w));
  }

  {
    f32x4 eacc = {0.f, 0.f, 0.f, 0.f};
    const u16* wl = wlB + lr * 256 + kg * 8;
#pragma unroll
    for (int ks = 0; ks < 8; ++ks) {
      union { bf16x8 v; uint4 q; } af, wf;
      af.q = a[ks];
      wf.q = *(const uint4*)(wl + ks * 32);
      eacc = __builtin_amdgcn_mfma_f32_16x16x32_bf16(af.v, wf.v, eacc, 0, 0, 0);
    }
    if (lr < 4) {
#pragma unroll
      for (int r = 0; r < 4; ++r) {
        int grow = row0 + w * 16 + kg * 4 + r;
        if (grow < N2) el[(size_t)grow * 4 + lr] = eacc[r];
      }
    }
  }

  for (int strip = 0; strip < 4; ++strip) {
    __syncthreads();
    {
      const int brow = t >> 3;
      const int bc = (t & 7) * 32;
      const uint4* s = (const uint4*)(Bt + (size_t)(strip * 64 + brow) * 256 + bc);
      uint4* d = (uint4*)&bs[brow][bc];
      d[0] = s[0]; d[1] = s[1]; d[2] = s[2]; d[3] = s[3];
    }
    __syncthreads();

    f32x4 acc[4];
#pragma unroll
    for (int ct = 0; ct < 4; ++ct) acc[ct] = (f32x4){0.f, 0.f, 0.f, 0.f};
#pragma unroll
    for (int ks = 0; ks < 8; ++ks) {
      union { bf16x8 v; uint4 q; } af;
      af.q = a[ks];
#pragma unroll
      for (int ct = 0; ct < 4; ++ct) {
        union { bf16x8 v; uint4 q; } b;
        b.q = *(const uint4*)&bs[ct * 16 + lr][ks * 32 + kg * 8];
        acc[ct] = __builtin_amdgcn_mfma_f32_16x16x32_bf16(af.v, b.v, acc[ct], 0, 0, 0);
      }
    }

#pragma unroll
    for (int p = 0; p < 2; ++p) {
      __syncthreads();
      if ((w >> 2) == p) {
        const int lrow = (w & 3) * 16 + kg * 4;
#pragma unroll
        for (int ct = 0; ct < 4; ++ct)
#pragma unroll
          for (int r = 0; r < 4; ++r)
            bs[lrow + r][ct * 16 + lr] = f2bf(acc[ct][r]);
      }
      __syncthreads();
      const int lrow2 = t >> 3;
      const int c0 = (t & 7) * 8;
      const int grow = row0 + p * 64 + lrow2;
      if (grow < N2)
        *(uint4*)(C + (size_t)grow * 256 + strip * 64 + c0) =
            *(const uint4*)&bs[lrow2][c0];
    }
  }
}

// LDS-staged per-node sort: block covers 256 nodes' contiguous CSR range.
__global__ void L384_sort(const int* indptr, int* csr, int n) {
  __shared__ int buf[5120];
  const int t = threadIdx.x;
  const int node0 = blockIdx.x * 256;
  const int nEnd = (node0 + 256 < n) ? (node0 + 256) : n;
  if (node0 >= n) return;
  const int segL = indptr[node0];
  const int segR = indptr[nEnd];
  const int len = segR - segL;
  if (len <= 5120) {
    for (int i = t; i < len; i += 256) buf[i] = csr[segL + i];
    __syncthreads();
    const int node = node0 + t;
    if (node < n) {
      int p0 = indptr[node] - segL;
      int p1 = indptr[node + 1] - segL;
      for (int a = p0 + 1; a < p1; ++a) {
        int v = buf[a];
        int b = a - 1;
        while (b >= p0 && buf[b] > v) {
          buf[b + 1] = buf[b];
          --b;
        }
        buf[b + 1] = v;
      }
    }
    __syncthreads();
    for (int i = t; i < len; i += 256) csr[segL + i] = buf[i];
  } else {
    const int node = node0 + t;
    if (node < n) {
      int p0 = indptr[node], p1 = indptr[node + 1];
      for (int a = p0 + 1; a < p1; ++a) {
        int v = csr[a];
        int b = a - 1;
        while (b >= p0 && csr[b] > v) {
          csr[b + 1] = csr[b];
          --b;
        }
        csr[b + 1] = v;
      }
    }
  }
}

// fused edge-softmax + aggregation: one wave per dst node.
// aL layout [slot][edge][head]: conflict-free broadcast reads in phase B.
__global__ void L384_aggx(const int* indptr, const int* csr, const float* el,
                          const float* er, const u16* fs, const float* bias,
                          float* alphaG, u16* X) {
  __shared__ float aL[4][64][4];
  __shared__ int sL[4][64];
  const int slot = threadIdx.x >> 6;
  const int wid = blockIdx.x * 4 + slot;
  const int lane = threadIdx.x & 63;
  if (wid >= N2) return;
  const int p0 = indptr[wid];
  const int deg = indptr[wid + 1] - p0;
  const int h = lane >> 4;
  const int c = lane & 15;
  float4 er4 = ld4(er + (size_t)wid * 4);

  const bool small = (deg <= 64);
  if (small) {
    float4 ex = {0.f, 0.f, 0.f, 0.f};
    int s = 0;
    if (lane < deg) {
      s = csr[p0 + lane];
      s = ((unsigned)s < N2) ? s : 0;
      float4 ev = ld4(el + (size_t)s * 4);
      float e0 = ev.x + er4.x; e0 = (e0 >= 0.f) ? e0 : 0.2f * e0;
      float e1 = ev.y + er4.y; e1 = (e1 >= 0.f) ? e1 : 0.2f * e1;
      float e2 = ev.z + er4.z; e2 = (e2 >= 0.f) ? e2 : 0.2f * e2;
      float e3 = ev.w + er4.w; e3 = (e3 >= 0.f) ? e3 : 0.2f * e3;
      ex = make_float4(__expf(e0), __expf(e1), __expf(e2), __expf(e3));
    }
    float d0 = ex.x, d1 = ex.y, d2 = ex.z, d3 = ex.w;
    for (int off = 32; off; off >>= 1) {
      d0 += __shfl_xor(d0, off);
      d1 += __shfl_xor(d1, off);
      d2 += __shfl_xor(d2, off);
      d3 += __shfl_xor(d3, off);
    }
    if (lane < deg) {
      float4 o = make_float4(ex.x / d0, ex.y / d1, ex.z / d2, ex.w / d3);
      *(float4*)&aL[slot][lane][0] = o;
      sL[slot][lane] = s;
    }
  } else if (deg > 0) {
    float d0 = 0.f, d1 = 0.f, d2 = 0.f, d3 = 0.f;
    for (int i = lane; i < deg; i += 64) {
      int s = csr[p0 + i];
      s = ((unsigned)s < N2) ? s : 0;
      float4 ev = ld4(el + (size_t)s * 4);
      float e0 = ev.x + er4.x; e0 = (e0 >= 0.f) ? e0 : 0.2f * e0;
      float e1 = ev.y + er4.y; e1 = (e1 >= 0.f) ? e1 : 0.2f * e1;
      float e2 = ev.z + er4.z; e2 = (e2 >= 0.f) ? e2 : 0.2f * e2;
      float e3 = ev.w + er4.w; e3 = (e3 >= 0.f) ? e3 : 0.2f * e3;
      float4 ex = make_float4(__expf(e0), __expf(e1), __expf(e2), __expf(e3));
      *(float4*)(alphaG + (size_t)(p0 + i) * 4) = ex;
      d0 += ex.x; d1 += ex.y; d2 += ex.z; d3 += ex.w;
    }
    for (int off = 32; off; off >>= 1) {
      d0 += __shfl_xor(d0, off);
      d1 += __shfl_xor(d1, off);
      d2 += __shfl_xor(d2, off);
      d3 += __shfl_xor(d3, off);
    }
    float i0 = 1.f / d0, i1 = 1.f / d1, i2 = 1.f / d2, i3 = 1.f / d3;
    for (int i = lane; i < deg; i += 64) {
      float4 ex = *(const float4*)(alphaG + (size_t)(p0 + i) * 4);
      *(float4*)(alphaG + (size_t)(p0 + i) * 4) =
          make_float4(ex.x * i0, ex.y * i1, ex.z * i2, ex.w * i3);
    }
  }

  float ax = 0.f, ay = 0.f, az = 0.f, aw = 0.f;
  int i = 0;
  for (; i + 4 <= deg; i += 4) {
    int s0, s1, s2, s3;
    float a0, a1, a2, a3;
    if (small) {
      s0 = sL[slot][i + 0]; s1 = sL[slot][i + 1];
      s2 = sL[slot][i + 2]; s3 = sL[slot][i + 3];
      a0 = aL[slot][i + 0][h]; a1 = aL[slot][i + 1][h];
      a2 = aL[slot][i + 2][h]; a3 = aL[slot][i + 3][h];
    } else {
      s0 = csr[p0 + i + 0]; s0 = ((unsigned)s0 < N2) ? s0 : 0;
      s1 = csr[p0 + i + 1]; s1 = ((unsigned)s1 < N2) ? s1 : 0;
      s2 = csr[p0 + i + 2]; s2 = ((unsigned)s2 < N2) ? s2 : 0;
      s3 = csr[p0 + i + 3]; s3 = ((unsigned)s3 < N2) ? s3 : 0;
      a0 = alphaG[(size_t)(p0 + i + 0) * 4 + h];
      a1 = alphaG[(size_t)(p0 + i + 1) * 4 + h];
      a2 = alphaG[(size_t)(p0 + i + 2) * 4 + h];
      a3 = alphaG[(size_t)(p0 + i + 3) * 4 + h];
    }
    uint2 q0 = *(const uint2*)(fs + (size_t)s0 * 256 + lane * 4);
    uint2 q1 = *(const uint2*)(fs + (size_t)s1 * 256 + lane * 4);
    uint2 q2 = *(const uint2*)(fs + (size_t)s2 * 256 + lane * 4);
    uint2 q3 = *(const uint2*)(fs + (size_t)s3 * 256 + lane * 4);
    ax += a0 * __uint_as_float(q0.x << 16);
    ay += a0 * __uint_as_float(q0.x & 0xffff0000u);
    az += a0 * __uint_as_float(q0.y << 16);
    aw += a0 * __uint_as_float(q0.y & 0xffff0000u);
    ax += a1 * __uint_as_float(q1.x << 16);
    ay += a1 * __uint_as_float(q1.x & 0xffff0000u);
    az += a1 * __uint_as_float(q1.y << 16);
    aw += a1 * __uint_as_float(q1.y & 0xffff0000u);
    ax += a2 * __uint_as_float(q2.x << 16);
    ay += a2 * __uint_as_float(q2.x & 0xffff0000u);
    az += a2 * __uint_as_float(q2.y << 16);
    aw += a2 * __uint_as_float(q2.y & 0xffff0000u);
    ax += a3 * __uint_as_float(q3.x << 16);
    ay += a3 * __uint_as_float(q3.x & 0xffff0000u);
    az += a3 * __uint_as_float(q3.y << 16);
    aw += a3 * __uint_as_float(q3.y & 0xffff0000u);
  }
  for (; i < deg; ++i) {
    int s0;
    float a0;
    if (small) {
      s0 = sL[slot][i];
      a0 = aL[slot][i][h];
    } else {
      s0 = csr[p0 + i]; s0 = ((unsigned)s0 < N2) ? s0 : 0;
      a0 = alphaG[(size_t)(p0 + i) * 4 + h];
    }
    uint2 q0 = *(const uint2*)(fs + (size_t)s0 * 256 + lane * 4);
    ax += a0 * __uint_as_float(q0.x << 16);
    ay += a0 * __uint_as_float(q0.x & 0xffff0000u);
    az += a0 * __uint_as_float(q0.y << 16);
    aw += a0 * __uint_as_float(q0.y & 0xffff0000u);
  }
  const float* bp = bias + lane * 4;
  float ox = ax + bp[0];
  float oy = ay + bp[1];
  float oz = az + bp[2];
  float ow = aw + bp[3];
  for (int off = 16; off <= 32; off <<= 1) {
    ox += __shfl_xor(ox, off);
    oy += __shfl_xor(oy, off);
    oz += __shfl_xor(oz, off);
    ow += __shfl_xor(ow, off);
  }
  if (h == 0) {
    uint2 pk = make_uint2(cvtpk(ox * 0.25f, oy * 0.25f), cvtpk(oz * 0.25f, ow * 0.25f));
    *(uint2*)(X + (size_t)wid * 320 + 4 * c) = pk;
  }
}

// head via MFMA: block = 64 rows, 4 waves x 32-col strips, 4 row-groups/wave.
__global__ void L384_headm(const u16* X, const u16* Wt, const float* Wb, float* out) {
  __shared__ float red[4][64];
  const int t = threadIdx.x;
  const int w = t >> 6;
  const int l = t & 63;
  const int row0 = blockIdx.x * 64;
  const int lr = l & 15;
  const int kg = l >> 4;
  f32x4 acc[4][2];
#pragma unroll
  for (int rg = 0; rg < 4; ++rg) {
    acc[rg][0] = (f32x4){0.f, 0.f, 0.f, 0.f};
    acc[rg][1] = (f32x4){0.f, 0.f, 0.f, 0.f};
  }
  const u16* arow[4];
#pragma unroll
  for (int rg = 0; rg < 4; ++rg) {
    int r = row0 + rg * 16 + lr;
    if (r >= N2) r = N2 - 1;
    arow[rg] = X + (size_t)r * 320 + kg * 8;
  }
  const u16* b0row = Wt + (size_t)(w * 32 + lr) * 320 + kg * 8;
  const u16* b1row = Wt + (size_t)(w * 32 + 16 + lr) * 320 + kg * 8;
#pragma unroll
  for (int k0 = 0; k0 < 320; k0 += 32) {
    union { bf16x8 v; uint4 q; } af[4], b0, b1;
#pragma unroll
    for (int rg = 0; rg < 4; ++rg) af[rg].q = *(const uint4*)(arow[rg] + k0);
    b0.q = *(const uint4*)(b0row + k0);
    b1.q = *(const uint4*)(b1row + k0);
#pragma unroll
    for (int rg = 0; rg < 4; ++rg) {
      acc[rg][0] = __builtin_amdgcn_mfma_f32_16x16x32_bf16(af[rg].v, b0.v,
                                                           acc[rg][0], 0, 0, 0);
      acc[rg][1] = __builtin_amdgcn_mfma_f32_16x16x32_bf16(af[rg].v, b1.v,
                                                           acc[rg][1], 0, 0, 0);
    }
  }
  const int col0 = w * 32 + lr;
  const int col1 = col0 + 16;
  float wb0 = Wb[col0], wb1 = Wb[col1];
  float z0[4][4], z1[4][4];
#pragma unroll
  for (int rg = 0; rg < 4; ++rg) {
    float pssq[4];
#pragma unroll
    for (int r = 0; r < 4; ++r) {
      z0[rg][r] = fmaxf(acc[rg][0][r] + wb0, 0.f);
      z1[rg][r] = fmaxf(acc[rg][1][r] + wb1, 0.f);
      pssq[r] = z0[rg][r] * z0[rg][r] + z1[rg][r] * z1[rg][r];
    }
#pragma unroll
    for (int off = 8; off; off >>= 1) {
#pragma unroll
      for (int r = 0; r < 4; ++r) pssq[r] += __shfl_xor(pssq[r], off);
    }
    if (lr == 0) {
#pragma unroll
      for (int r = 0; r < 4; ++r) red[w][rg * 16 + kg * 4 + r] = pssq[r];
    }
  }
  __syncthreads();
#pragma unroll
  for (int rg = 0; rg < 4; ++rg) {
#pragma unroll
    for (int r = 0; r < 4; ++r) {
      int lrow = rg * 16 + kg * 4 + r;
      int grow = row0 + lrow;
      if (grow < N2) {
        float ssq = red[0][lrow] + red[1][lrow] + red[2][lrow] + red[3][lrow];
        float inv = (ssq > 0.f) ? rsqrtf(ssq) : 0.f;
        float* op = out + (size_t)grow * 128;
        op[col0] = z0[rg][r] * inv;
        op[col1] = z1[rg][r] * inv;
      }
    }
  }
}

extern "C" void kernel_launch(void* const* d_in, const int* in_sizes, int n_in,
                              void* d_out, int out_size, void* d_ws, size_t ws_size,
                              hipStream_t stream) {
  (void)in_sizes; (void)n_in; (void)out_size; (void)ws_size;
  const float* h_src_user = (const float*)d_in[0];
  const float* h_src_item = (const float*)d_in[1];
  const float* h_dst_user = (const float*)d_in[2];
  const float* h_dst_item = (const float*)d_in[3];
  const int* u2i_src = (const int*)d_in[4];
  const int* u2i_dst = (const int*)d_in[5];
  const int* i2u_src = (const int*)d_in[6];
  const int* i2u_dst = (const int*)d_in[7];
  const float* fc_w = (const float*)d_in[8];
  const float* attn_l = (const float*)d_in[9];
  const float* attn_r = (const float*)d_in[10];
  const float* gat_bias = (const float*)d_in[11];
  const float* W_w = (const float*)d_in[12];
  const float* W_b = (const float*)d_in[13];
  float* out = (float*)d_out;  // f32 [2NN][128] = [z_user; z_item]

  float* el = (float*)d_ws;                     // N2*4
  float* er = el + (size_t)N2 * 4;              // N2*4
  float* w_r = er + (size_t)N2 * 4;             // 1024
  u16* wlB = (u16*)(w_r + 1024);                // 16*256
  float* alpha = (float*)(wlB + 16 * 256);      // E2*4 (fallback only)
  u16* fs = (u16*)(alpha + (size_t)E2 * 4);     // N2*256 bf16
  u16* X = fs + (size_t)N2 * 256;               // N2*320 bf16
  u16* Bt = X + (size_t)N2 * 320;               // 256*256
  u16* Wt = Bt + 256 * 256;                     // 128*320
  int* indptr = (int*)(Wt + 128 * 320);         // N2+1 (+pad)
  int* cur = indptr + (N2 + 4);                 // N2
  int* csr = cur + N2;                          // E2
  int* bsum = csr + E2;                         // 128

  // const + zero (fused)
  L384_const<<<776, 256, 0, stream>>>(fc_w, attn_l, attn_r, W_w, w_r, wlB, Bt, Wt, cur);
  // prep + hist (fused; hist hides in prep's shadow)
  L384_prep<<<28907, 256, 0, stream>>>(h_dst_user, h_dst_item, w_r, X, er,
                                       i2u_dst, u2i_dst, cur);
  L384_scan1<<<98, 256, 0, stream>>>(cur, indptr, bsum, N2);
  L384_scan23<<<391, 256, 0, stream>>>(indptr, bsum, cur, 98, N2);
  // gemm + fill (fused; fill hides in gemm's shadow)
  L384_gemm<<<2736, 512, 0, stream>>>(h_src_user, h_src_item, Bt, wlB, fs, el,
                                      i2u_src, i2u_dst, u2i_src, u2i_dst, cur, csr);
  L384_sort<<<391, 256, 0, stream>>>(indptr, csr, N2);
  L384_aggx<<<25000, 256, 0, stream>>>(indptr, csr, el, er, fs, gat_bias, alpha, X);
  L384_headm<<<1563, 256, 0, stream>>>(X, Wt, W_b, out);
}

// Round 40
// 348.124 us; speedup vs baseline: 1.7068x; 1.0459x over previous
//
#include <hip/hip_runtime.h>

#define NN 50000
#define N2 100000
#define EE 500000
#define E2 1000000

typedef unsigned short u16;
typedef unsigned int u32;

typedef __attribute__((ext_vector_type(8))) __bf16 bf16x8;
typedef __attribute__((ext_vector_type(4))) float f32x4;

__device__ __forceinline__ float4 ld4(const float* p) { return *(const float4*)p; }

// round-to-nearest-even f32 -> bf16 bits
__device__ __forceinline__ u16 f2bf(float f) {
  u32 u = __float_as_uint(f);
  u += 0x7FFFu + ((u >> 16) & 1u);
  return (u16)(u >> 16);
}

// HW packed convert: low16 = bf16(lo), high16 = bf16(hi) (RNE)
__device__ __forceinline__ u32 cvtpk(float lo, float hi) {
  u32 r;
  asm("v_cvt_pk_bf16_f32 %0, %1, %2" : "=v"(r) : "v"(lo), "v"(hi));
  return r;
}

// fused constants + cur-zero kernel:
//  blocks 0..255   : Bt transpose; 256: w_r/wlB; 257..384: Wt transpose
//  blocks 385..775 : cur[i] = 0
__global__ void L384_const(const float* fc_w, const float* attn_l,
                           const float* attn_r, const float* Ww, float* w_r,
                           u16* wlB, u16* Bt, u16* Wt, int* cur) {
  const int b = blockIdx.x;
  const int t = threadIdx.x;
  if (b < 256) {
    Bt[b * 256 + t] = f2bf(fc_w[(size_t)t * 256 + b]);
  } else if (b == 256) {
    for (int h = 0; h < 4; ++h) {
      float sl = 0.f, sr = 0.f;
      for (int d = 0; d < 64; ++d) {
        float f = fc_w[t * 256 + h * 64 + d];
        sl += f * attn_l[h * 64 + d];
        sr += f * attn_r[h * 64 + d];
      }
      w_r[t * 4 + h] = sr;
      wlB[h * 256 + t] = f2bf(sl);
    }
    for (int h = 4; h < 16; ++h) wlB[h * 256 + t] = 0;
  } else if (b < 385) {
    int n = b - 257;
    for (int k = t; k < 320; k += 256)
      Wt[(size_t)n * 320 + k] = f2bf(Ww[(size_t)k * 128 + n]);
  } else {
    int i = (b - 385) * 256 + t;
    if (i < N2) cur[i] = 0;
  }
}

// fused prep + hist:
//  blocks 0..24999     : X staging + er for dst rows
//  blocks 25000..28906 : degree histogram (atomics into cur)
__global__ void L384_prep(const float* Du, const float* Di, const float* w_r_,
                          u16* X, float* er, const int* i2u_dst,
                          const int* u2i_dst, int* cnt) {
  const int b = blockIdx.x;
  if (b >= 25000) {
    int e = (b - 25000) * 256 + threadIdx.x;
    if (e < EE) {
      int d = i2u_dst[e];
      d = ((unsigned)d < NN) ? d : 0;
      atomicAdd(&cnt[d], 1);
    } else if (e < E2) {
      int d = u2i_dst[e - EE];
      d = ((unsigned)d < NN) ? d : 0;
      atomicAdd(&cnt[NN + d], 1);
    }
    return;
  }
  const int r = b * 4 + (threadIdx.x >> 6);
  const int lane = threadIdx.x & 63;
  if (r >= N2) return;
  const float* src = (r < NN) ? Du + (size_t)r * 256 : Di + (size_t)(r - NN) * 256;
  float4 xv = ld4(src + lane * 4);
  uint2 pk = make_uint2(cvtpk(xv.x, xv.y), cvtpk(xv.z, xv.w));
  *(uint2*)(X + (size_t)r * 320 + 64 + lane * 4) = pk;
  const float* wr = w_r_ + lane * 16;
  float4 w0 = ld4(wr), w1 = ld4(wr + 4), w2 = ld4(wr + 8), w3 = ld4(wr + 12);
  float a0 = xv.x * w0.x + xv.y * w1.x + xv.z * w2.x + xv.w * w3.x;
  float a1 = xv.x * w0.y + xv.y * w1.y + xv.z * w2.y + xv.w * w3.y;
  float a2 = xv.x * w0.z + xv.y * w1.z + xv.z * w2.z + xv.w * w3.z;
  float a3 = xv.x * w0.w + xv.y * w1.w + xv.z * w2.w + xv.w * w3.w;
  for (int off = 32; off; off >>= 1) {
    a0 += __shfl_xor(a0, off);
    a1 += __shfl_xor(a1, off);
    a2 += __shfl_xor(a2, off);
    a3 += __shfl_xor(a3, off);
  }
  if (lane == 0) {
    float* op = er + (size_t)r * 4;
    op[0] = a0; op[1] = a1; op[2] = a2; op[3] = a3;
  }
}

__global__ void L384_scan1(const int* cnt, int* part, int* bsum, int n) {
  __shared__ int sh[256];
  const int t = threadIdx.x;
  const int base = blockIdx.x * 1024 + t * 4;
  int v0 = (base + 0 < n) ? cnt[base + 0] : 0;
  int v1 = (base + 1 < n) ? cnt[base + 1] : 0;
  int v2 = (base + 2 < n) ? cnt[base + 2] : 0;
  int v3 = (base + 3 < n) ? cnt[base + 3] : 0;
  int s0 = v0, s1 = s0 + v1, s2 = s1 + v2, s3 = s2 + v3;
  sh[t] = s3;
  __syncthreads();
  for (int off = 1; off < 256; off <<= 1) {
    int x = (t >= off) ? sh[t - off] : 0;
    __syncthreads();
    sh[t] += x;
    __syncthreads();
  }
  int excl = (t > 0) ? sh[t - 1] : 0;
  if (base + 0 < n) part[base + 0] = excl;
  if (base + 1 < n) part[base + 1] = excl + s0;
  if (base + 2 < n) part[base + 2] = excl + s1;
  if (base + 3 < n) part[base + 3] = excl + s2;
  if (t == 255) bsum[blockIdx.x] = sh[255];
}
// fused scan2+scan3: per-block replicated 98-entry bsum prefix, then distribute.
__global__ void L384_scan23(int* indptr, const int* bsum, int* cur, int nb, int n) {
  __shared__ int pre[128];
  const int t = threadIdx.x;
  if (t == 0) {
    int acc = 0;
    for (int i = 0; i < nb; ++i) {
      pre[i] = acc;
      acc += bsum[i];
    }
    pre[nb] = acc;
  }
  __syncthreads();
  int i = blockIdx.x * 256 + t;
  if (i < n) {
    int v = indptr[i] + pre[i >> 10];
    indptr[i] = v;
    cur[i] = v;
  }
  if (blockIdx.x == 0 && t == 0) indptr[n] = pre[nb];
}
__global__ void L384_fill(const int* i2u_src, const int* i2u_dst,
                          const int* u2i_src, const int* u2i_dst,
                          int* cur, int* csr) {
  int e = blockIdx.x * 256 + threadIdx.x;
  if (e < EE) {
    int d = i2u_dst[e];
    d = ((unsigned)d < NN) ? d : 0;
    int s = i2u_src[e];
    s = ((unsigned)s < NN) ? s : 0;
    int pos = atomicAdd(&cur[d], 1);
    if ((unsigned)pos < E2) csr[pos] = NN + s;
  } else if (e < E2) {
    int d = u2i_dst[e - EE];
    d = ((unsigned)d < NN) ? d : 0;
    int s = u2i_src[e - EE];
    s = ((unsigned)s < NN) ? s : 0;
    int pos = atomicAdd(&cur[NN + d], 1);
    if ((unsigned)pos < E2) csr[pos] = s;
  }
}

// gemm: fs = bf16(Asrc) @ fc_w; el = Asrc @ w_l (wlB MFMA, once per block).
__global__ __launch_bounds__(512) void L384_gemm(const float* Au, const float* Ai,
                                                 const u16* Bt, const u16* wlB,
                                                 u16* C, float* el) {
  __shared__ u16 bs[64][264];
  const int t = threadIdx.x;
  const int w = t >> 6;
  const int l = t & 63;
  const int lr = l & 15;
  const int kg = l >> 4;
  const int row0 = blockIdx.x * 128;

  const int row = row0 + w * 16 + lr;
  const int rr = (row < N2) ? row : (N2 - 1);
  const float* arow =
      ((rr < NN) ? Au + (size_t)rr * 256 : Ai + (size_t)(rr - NN) * 256) + kg * 8;
  uint4 a[8];
#pragma unroll
  for (int ks = 0; ks < 8; ++ks) {
    float4 f0 = ld4(arow + ks * 32);
    float4 f1 = ld4(arow + ks * 32 + 4);
    a[ks] = make_uint4(cvtpk(f0.x, f0.y), cvtpk(f0.z, f0.w), cvtpk(f1.x, f1.y),
                       cvtpk(f1.z, f1.w));
  }

  {
    f32x4 eacc = {0.f, 0.f, 0.f, 0.f};
    const u16* wl = wlB + lr * 256 + kg * 8;
#pragma unroll
    for (int ks = 0; ks < 8; ++ks) {
      union { bf16x8 v; uint4 q; } af, wf;
      af.q = a[ks];
      wf.q = *(const uint4*)(wl + ks * 32);
      eacc = __builtin_amdgcn_mfma_f32_16x16x32_bf16(af.v, wf.v, eacc, 0, 0, 0);
    }
    if (lr < 4) {
#pragma unroll
      for (int r = 0; r < 4; ++r) {
        int grow = row0 + w * 16 + kg * 4 + r;
        if (grow < N2) el[(size_t)grow * 4 + lr] = eacc[r];
      }
    }
  }

  for (int strip = 0; strip < 4; ++strip) {
    __syncthreads();
    {
      const int brow = t >> 3;
      const int bc = (t & 7) * 32;
      const uint4* s = (const uint4*)(Bt + (size_t)(strip * 64 + brow) * 256 + bc);
      uint4* d = (uint4*)&bs[brow][bc];
      d[0] = s[0]; d[1] = s[1]; d[2] = s[2]; d[3] = s[3];
    }
    __syncthreads();

    f32x4 acc[4];
#pragma unroll
    for (int ct = 0; ct < 4; ++ct) acc[ct] = (f32x4){0.f, 0.f, 0.f, 0.f};
#pragma unroll
    for (int ks = 0; ks < 8; ++ks) {
      union { bf16x8 v; uint4 q; } af;
      af.q = a[ks];
#pragma unroll
      for (int ct = 0; ct < 4; ++ct) {
        union { bf16x8 v; uint4 q; } b;
        b.q = *(const uint4*)&bs[ct * 16 + lr][ks * 32 + kg * 8];
        acc[ct] = __builtin_amdgcn_mfma_f32_16x16x32_bf16(af.v, b.v, acc[ct], 0, 0, 0);
      }
    }

#pragma unroll
    for (int p = 0; p < 2; ++p) {
      __syncthreads();
      if ((w >> 2) == p) {
        const int lrow = (w & 3) * 16 + kg * 4;
#pragma unroll
        for (int ct = 0; ct < 4; ++ct)
#pragma unroll
          for (int r = 0; r < 4; ++r)
            bs[lrow + r][ct * 16 + lr] = f2bf(acc[ct][r]);
      }
      __syncthreads();
      const int lrow2 = t >> 3;
      const int c0 = (t & 7) * 8;
      const int grow = row0 + p * 64 + lrow2;
      if (grow < N2)
        *(uint4*)(C + (size_t)grow * 256 + strip * 64 + c0) =
            *(const uint4*)&bs[lrow2][c0];
    }
  }
}

// fused edge-softmax + aggregation: one wave per dst node.
// Phase A sorts the wave's <=64 edge indices with an in-wave bitonic network
// (ascending; deterministic, replaces the global sort kernel), then parallel
// exp/lrelu + butterfly den, storing alpha/src in LDS for phase B.
__global__ void L384_aggx(const int* indptr, const int* csr, const float* el,
                          const float* er, const u16* fs, const float* bias,
                          float* alphaG, u16* X) {
  __shared__ float aL[4][64][4];
  __shared__ int sL[4][64];
  const int slot = threadIdx.x >> 6;
  const int wid = blockIdx.x * 4 + slot;
  const int lane = threadIdx.x & 63;
  if (wid >= N2) return;
  const int p0 = indptr[wid];
  const int deg = indptr[wid + 1] - p0;
  const int h = lane >> 4;
  const int c = lane & 15;
  float4 er4 = ld4(er + (size_t)wid * 4);

  const bool small = (deg <= 64);
  if (small) {
    int s = 0x7fffffff;  // sentinel sorts to the tail
    if (lane < deg) {
      s = csr[p0 + lane];
      s = ((unsigned)s < N2) ? s : 0;
    }
    // 64-lane bitonic ascending sort (21 compare-exchange stages)
#pragma unroll
    for (int k = 2; k <= 64; k <<= 1) {
#pragma unroll
      for (int j = k >> 1; j > 0; j >>= 1) {
        int o = __shfl_xor(s, j);
        bool up = ((lane & k) == 0);
        bool keepMin = (((lane & j) == 0) == up);
        int mn = (s < o) ? s : o;
        int mx = (s < o) ? o : s;
        s = keepMin ? mn : mx;
      }
    }
    float4 ex = {0.f, 0.f, 0.f, 0.f};
    if (lane < deg) {
      float4 ev = ld4(el + (size_t)s * 4);
      float e0 = ev.x + er4.x; e0 = (e0 >= 0.f) ? e0 : 0.2f * e0;
      float e1 = ev.y + er4.y; e1 = (e1 >= 0.f) ? e1 : 0.2f * e1;
      float e2 = ev.z + er4.z; e2 = (e2 >= 0.f) ? e2 : 0.2f * e2;
      float e3 = ev.w + er4.w; e3 = (e3 >= 0.f) ? e3 : 0.2f * e3;
      ex = make_float4(__expf(e0), __expf(e1), __expf(e2), __expf(e3));
    }
    float d0 = ex.x, d1 = ex.y, d2 = ex.z, d3 = ex.w;
    for (int off = 32; off; off >>= 1) {
      d0 += __shfl_xor(d0, off);
      d1 += __shfl_xor(d1, off);
      d2 += __shfl_xor(d2, off);
      d3 += __shfl_xor(d3, off);
    }
    if (lane < deg) {
      float4 o = make_float4(ex.x / d0, ex.y / d1, ex.z / d2, ex.w / d3);
      *(float4*)&aL[slot][lane][0] = o;
      sL[slot][lane] = s;
    }
  } else if (deg > 0) {
    // fallback (never hit at Poisson(10) degrees): unsorted order, 2-pass
    float d0 = 0.f, d1 = 0.f, d2 = 0.f, d3 = 0.f;
    for (int i = lane; i < deg; i += 64) {
      int s = csr[p0 + i];
      s = ((unsigned)s < N2) ? s : 0;
      float4 ev = ld4(el + (size_t)s * 4);
      float e0 = ev.x + er4.x; e0 = (e0 >= 0.f) ? e0 : 0.2f * e0;
      float e1 = ev.y + er4.y; e1 = (e1 >= 0.f) ? e1 : 0.2f * e1;
      float e2 = ev.z + er4.z; e2 = (e2 >= 0.f) ? e2 : 0.2f * e2;
      float e3 = ev.w + er4.w; e3 = (e3 >= 0.f) ? e3 : 0.2f * e3;
      float4 ex = make_float4(__expf(e0), __expf(e1), __expf(e2), __expf(e3));
      *(float4*)(alphaG + (size_t)(p0 + i) * 4) = ex;
      d0 += ex.x; d1 += ex.y; d2 += ex.z; d3 += ex.w;
    }
    for (int off = 32; off; off >>= 1) {
      d0 += __shfl_xor(d0, off);
      d1 += __shfl_xor(d1, off);
      d2 += __shfl_xor(d2, off);
      d3 += __shfl_xor(d3, off);
    }
    float i0 = 1.f / d0, i1 = 1.f / d1, i2 = 1.f / d2, i3 = 1.f / d3;
    for (int i = lane; i < deg; i += 64) {
      float4 ex = *(const float4*)(alphaG + (size_t)(p0 + i) * 4);
      *(float4*)(alphaG + (size_t)(p0 + i) * 4) =
          make_float4(ex.x * i0, ex.y * i1, ex.z * i2, ex.w * i3);
    }
  }

  float ax = 0.f, ay = 0.f, az = 0.f, aw = 0.f;
  int i = 0;
  for (; i + 4 <= deg; i += 4) {
    int s0, s1, s2, s3;
    float a0, a1, a2, a3;
    if (small) {
      s0 = sL[slot][i + 0]; s1 = sL[slot][i + 1];
      s2 = sL[slot][i + 2]; s3 = sL[slot][i + 3];
      a0 = aL[slot][i + 0][h]; a1 = aL[slot][i + 1][h];
      a2 = aL[slot][i + 2][h]; a3 = aL[slot][i + 3][h];
    } else {
      s0 = csr[p0 + i + 0]; s0 = ((unsigned)s0 < N2) ? s0 : 0;
      s1 = csr[p0 + i + 1]; s1 = ((unsigned)s1 < N2) ? s1 : 0;
      s2 = csr[p0 + i + 2]; s2 = ((unsigned)s2 < N2) ? s2 : 0;
      s3 = csr[p0 + i + 3]; s3 = ((unsigned)s3 < N2) ? s3 : 0;
      a0 = alphaG[(size_t)(p0 + i + 0) * 4 + h];
      a1 = alphaG[(size_t)(p0 + i + 1) * 4 + h];
      a2 = alphaG[(size_t)(p0 + i + 2) * 4 + h];
      a3 = alphaG[(size_t)(p0 + i + 3) * 4 + h];
    }
    uint2 q0 = *(const uint2*)(fs + (size_t)s0 * 256 + lane * 4);
    uint2 q1 = *(const uint2*)(fs + (size_t)s1 * 256 + lane * 4);
    uint2 q2 = *(const uint2*)(fs + (size_t)s2 * 256 + lane * 4);
    uint2 q3 = *(const uint2*)(fs + (size_t)s3 * 256 + lane * 4);
    ax += a0 * __uint_as_float(q0.x << 16);
    ay += a0 * __uint_as_float(q0.x & 0xffff0000u);
    az += a0 * __uint_as_float(q0.y << 16);
    aw += a0 * __uint_as_float(q0.y & 0xffff0000u);
    ax += a1 * __uint_as_float(q1.x << 16);
    ay += a1 * __uint_as_float(q1.x & 0xffff0000u);
    az += a1 * __uint_as_float(q1.y << 16);
    aw += a1 * __uint_as_float(q1.y & 0xffff0000u);
    ax += a2 * __uint_as_float(q2.x << 16);
    ay += a2 * __uint_as_float(q2.x & 0xffff0000u);
    az += a2 * __uint_as_float(q2.y << 16);
    aw += a2 * __uint_as_float(q2.y & 0xffff0000u);
    ax += a3 * __uint_as_float(q3.x << 16);
    ay += a3 * __uint_as_float(q3.x & 0xffff0000u);
    az += a3 * __uint_as_float(q3.y << 16);
    aw += a3 * __uint_as_float(q3.y & 0xffff0000u);
  }
  for (; i < deg; ++i) {
    int s0;
    float a0;
    if (small) {
      s0 = sL[slot][i];
      a0 = aL[slot][i][h];
    } else {
      s0 = csr[p0 + i]; s0 = ((unsigned)s0 < N2) ? s0 : 0;
      a0 = alphaG[(size_t)(p0 + i) * 4 + h];
    }
    uint2 q0 = *(const uint2*)(fs + (size_t)s0 * 256 + lane * 4);
    ax += a0 * __uint_as_float(q0.x << 16);
    ay += a0 * __uint_as_float(q0.x & 0xffff0000u);
    az += a0 * __uint_as_float(q0.y << 16);
    aw += a0 * __uint_as_float(q0.y & 0xffff0000u);
  }
  const float* bp = bias + lane * 4;
  float ox = ax + bp[0];
  float oy = ay + bp[1];
  float oz = az + bp[2];
  float ow = aw + bp[3];
  for (int off = 16; off <= 32; off <<= 1) {
    ox += __shfl_xor(ox, off);
    oy += __shfl_xor(oy, off);
    oz += __shfl_xor(oz, off);
    ow += __shfl_xor(ow, off);
  }
  if (h == 0) {
    uint2 pk = make_uint2(cvtpk(ox * 0.25f, oy * 0.25f), cvtpk(oz * 0.25f, ow * 0.25f));
    *(uint2*)(X + (size_t)wid * 320 + 4 * c) = pk;
  }
}

// head via MFMA: block = 64 rows, 4 waves x 32-col strips, 4 row-groups/wave.
__global__ void L384_headm(const u16* X, const u16* Wt, const float* Wb, float* out) {
  __shared__ float red[4][64];
  const int t = threadIdx.x;
  const int w = t >> 6;
  const int l = t & 63;
  const int row0 = blockIdx.x * 64;
  const int lr = l & 15;
  const int kg = l >> 4;
  f32x4 acc[4][2];
#pragma unroll
  for (int rg = 0; rg < 4; ++rg) {
    acc[rg][0] = (f32x4){0.f, 0.f, 0.f, 0.f};
    acc[rg][1] = (f32x4){0.f, 0.f, 0.f, 0.f};
  }
  const u16* arow[4];
#pragma unroll
  for (int rg = 0; rg < 4; ++rg) {
    int r = row0 + rg * 16 + lr;
    if (r >= N2) r = N2 - 1;
    arow[rg] = X + (size_t)r * 320 + kg * 8;
  }
  const u16* b0row = Wt + (size_t)(w * 32 + lr) * 320 + kg * 8;
  const u16* b1row = Wt + (size_t)(w * 32 + 16 + lr) * 320 + kg * 8;
#pragma unroll
  for (int k0 = 0; k0 < 320; k0 += 32) {
    union { bf16x8 v; uint4 q; } af[4], b0, b1;
#pragma unroll
    for (int rg = 0; rg < 4; ++rg) af[rg].q = *(const uint4*)(arow[rg] + k0);
    b0.q = *(const uint4*)(b0row + k0);
    b1.q = *(const uint4*)(b1row + k0);
#pragma unroll
    for (int rg = 0; rg < 4; ++rg) {
      acc[rg][0] = __builtin_amdgcn_mfma_f32_16x16x32_bf16(af[rg].v, b0.v,
                                                           acc[rg][0], 0, 0, 0);
      acc[rg][1] = __builtin_amdgcn_mfma_f32_16x16x32_bf16(af[rg].v, b1.v,
                                                           acc[rg][1], 0, 0, 0);
    }
  }
  const int col0 = w * 32 + lr;
  const int col1 = col0 + 16;
  float wb0 = Wb[col0], wb1 = Wb[col1];
  float z0[4][4], z1[4][4];
#pragma unroll
  for (int rg = 0; rg < 4; ++rg) {
    float pssq[4];
#pragma unroll
    for (int r = 0; r < 4; ++r) {
      z0[rg][r] = fmaxf(acc[rg][0][r] + wb0, 0.f);
      z1[rg][r] = fmaxf(acc[rg][1][r] + wb1, 0.f);
      pssq[r] = z0[rg][r] * z0[rg][r] + z1[rg][r] * z1[rg][r];
    }
#pragma unroll
    for (int off = 8; off; off >>= 1) {
#pragma unroll
      for (int r = 0; r < 4; ++r) pssq[r] += __shfl_xor(pssq[r], off);
    }
    if (lr == 0) {
#pragma unroll
      for (int r = 0; r < 4; ++r) red[w][rg * 16 + kg * 4 + r] = pssq[r];
    }
  }
  __syncthreads();
#pragma unroll
  for (int rg = 0; rg < 4; ++rg) {
#pragma unroll
    for (int r = 0; r < 4; ++r) {
      int lrow = rg * 16 + kg * 4 + r;
      int grow = row0 + lrow;
      if (grow < N2) {
        float ssq = red[0][lrow] + red[1][lrow] + red[2][lrow] + red[3][lrow];
        float inv = (ssq > 0.f) ? rsqrtf(ssq) : 0.f;
        float* op = out + (size_t)grow * 128;
        op[col0] = z0[rg][r] * inv;
        op[col1] = z1[rg][r] * inv;
      }
    }
  }
}

extern "C" void kernel_launch(void* const* d_in, const int* in_sizes, int n_in,
                              void* d_out, int out_size, void* d_ws, size_t ws_size,
                              hipStream_t stream) {
  (void)in_sizes; (void)n_in; (void)out_size; (void)ws_size;
  const float* h_src_user = (const float*)d_in[0];
  const float* h_src_item = (const float*)d_in[1];
  const float* h_dst_user = (const float*)d_in[2];
  const float* h_dst_item = (const float*)d_in[3];
  const int* u2i_src = (const int*)d_in[4];
  const int* u2i_dst = (const int*)d_in[5];
  const int* i2u_src = (const int*)d_in[6];
  const int* i2u_dst = (const int*)d_in[7];
  const float* fc_w = (const float*)d_in[8];
  const float* attn_l = (const float*)d_in[9];
  const float* attn_r = (const float*)d_in[10];
  const float* gat_bias = (const float*)d_in[11];
  const float* W_w = (const float*)d_in[12];
  const float* W_b = (const float*)d_in[13];
  float* out = (float*)d_out;  // f32 [2NN][128] = [z_user; z_item]

  float* el = (float*)d_ws;                     // N2*4
  float* er = el + (size_t)N2 * 4;              // N2*4
  float* w_r = er + (size_t)N2 * 4;             // 1024
  u16* wlB = (u16*)(w_r + 1024);                // 16*256
  float* alpha = (float*)(wlB + 16 * 256);      // E2*4 (fallback only)
  u16* fs = (u16*)(alpha + (size_t)E2 * 4);     // N2*256 bf16
  u16* X = fs + (size_t)N2 * 256;               // N2*320 bf16
  u16* Bt = X + (size_t)N2 * 320;               // 256*256
  u16* Wt = Bt + 256 * 256;                     // 128*320
  int* indptr = (int*)(Wt + 128 * 320);         // N2+1 (+pad)
  int* cur = indptr + (N2 + 4);                 // N2
  int* csr = cur + N2;                          // E2
  int* bsum = csr + E2;                         // 128

  // const + zero (fused)
  L384_const<<<776, 256, 0, stream>>>(fc_w, attn_l, attn_r, W_w, w_r, wlB, Bt, Wt, cur);
  // prep + hist (fused; hist hides in prep's shadow)
  L384_prep<<<28907, 256, 0, stream>>>(h_dst_user, h_dst_item, w_r, X, er,
                                       i2u_dst, u2i_dst, cur);
  L384_scan1<<<98, 256, 0, stream>>>(cur, indptr, bsum, N2);
  L384_scan23<<<391, 256, 0, stream>>>(indptr, bsum, cur, 98, N2);
  L384_fill<<<3907, 256, 0, stream>>>(i2u_src, i2u_dst, u2i_src, u2i_dst, cur, csr);
  L384_gemm<<<782, 512, 0, stream>>>(h_src_user, h_src_item, Bt, wlB, fs, el);
  // sort kernel eliminated: aggx does in-wave bitonic sort (deg<=64 path)
  L384_aggx<<<25000, 256, 0, stream>>>(indptr, csr, el, er, fs, gat_bias, alpha, X);
  L384_headm<<<1563, 256, 0, stream>>>(X, Wt, W_b, out);
}